// Round 2
// baseline (272.979 us; speedup 1.0000x reference)
//
#include <hip/hip_runtime.h>
#include <hip/hip_bf16.h>
#include <math.h>

// Problem: B=2, N=2048, D_MODEL=1024, H=16, D_HEAD=64. fp32 in/out,
// bf16 MFMA internal (threshold is bf16-grade: 2% of max|ref|).
#define BATCH 2
#define NSEQ  2048
#define DM    1024
#define NH    16
#define DH    64
#define EPS_N 1e-6f

typedef unsigned short u16;
typedef __attribute__((ext_vector_type(8))) short short8;       // bf16x8 MFMA frag
typedef __attribute__((ext_vector_type(8))) unsigned short u16x8;
typedef __attribute__((ext_vector_type(4))) unsigned short u16x4;
typedef __attribute__((ext_vector_type(4))) float f32x4;

__device__ __forceinline__ u16 f2bf(float x) {
  __hip_bfloat16 h = __float2bfloat16(x);          // round-to-nearest-even
  return *reinterpret_cast<u16*>(&h);
}

// async 16B global->LDS (lane i lands at lds_base + 16*i)
__device__ __forceinline__ void gl_lds16(const u16* g, u16* lds_base) {
  __builtin_amdgcn_global_load_lds(
      (__attribute__((address_space(1))) void*)g,
      (__attribute__((address_space(3))) void*)lds_base, 16, 0, 0);
}

// ---------------------------------------------------------------------------
// Prep: blocks 0..1023 transpose+cast the 4 weight matrices (out[n][k] =
// bf16(in[k][n])); blocks 1024..3071 cast X fp32->bf16. grid 3072, 256 thr.
// ---------------------------------------------------------------------------
__global__ __launch_bounds__(256) void prep(
    const float* __restrict__ X,
    const float* __restrict__ w0, const float* __restrict__ w1,
    const float* __restrict__ w2, const float* __restrict__ w3,
    u16* __restrict__ Xb, u16* __restrict__ WT) {
  const int id = blockIdx.x, tid = threadIdx.x;
  if (id >= 1024) {                       // ---- cast X chunk
    size_t base = ((size_t)(id - 1024) * 256 + tid) * 8;
    float4 f0 = *(const float4*)&X[base];
    float4 f1 = *(const float4*)&X[base + 4];
    u16x8 v;
    v[0] = f2bf(f0.x); v[1] = f2bf(f0.y); v[2] = f2bf(f0.z); v[3] = f2bf(f0.w);
    v[4] = f2bf(f1.x); v[5] = f2bf(f1.y); v[6] = f2bf(f1.z); v[7] = f2bf(f1.w);
    *(u16x8*)&Xb[base] = v;
    return;
  }
  // ---- weight transpose tile
  const int z = id >> 8, xy = id & 255, bx = xy & 15, by = xy >> 4;
  const float* in = (z == 0) ? w0 : (z == 1) ? w1 : (z == 2) ? w2 : w3;
  u16* o = WT + (size_t)z * DM * DM;
  __shared__ u16 T[64][65];
  const int n0 = bx * 64, k0 = by * 64;
  #pragma unroll
  for (int i = 0; i < 4; i++) {
    int c = tid + 256 * i, row = c >> 4, col4 = c & 15;
    float4 f = *(const float4*)&in[(size_t)(k0 + row) * DM + n0 + col4 * 4];
    T[row][col4 * 4 + 0] = f2bf(f.x);
    T[row][col4 * 4 + 1] = f2bf(f.y);
    T[row][col4 * 4 + 2] = f2bf(f.z);
    T[row][col4 * 4 + 3] = f2bf(f.w);
  }
  __syncthreads();
  #pragma unroll
  for (int i = 0; i < 2; i++) {
    int c = tid + 256 * i, row = c >> 3, col8 = c & 7;
    u16x8 v;
    #pragma unroll
    for (int e = 0; e < 8; e++) v[e] = T[col8 * 8 + e][row];
    *(u16x8*)&o[(size_t)(n0 + row) * DM + k0 + col8 * 8] = v;
  }
}

// ===========================================================================
// m97-style 128x128 GEMM mainloop (BK=64, global_load_lds 16B, XOR-swizzled
// LDS chunks). A[m][k], Bt[n][k] both bf16. 256 thr, 4 waves in 2x2 (wm,wn).
// LDS: row r (128 B) holds global chunk g at position g^(r&7).
// ===========================================================================
#define GEMM128_MAINLOOP(Aptr, Btptr)                                          \
  __shared__ u16 As[128 * 64];                                                 \
  __shared__ u16 Bs[128 * 64];                                                 \
  const int tid = threadIdx.x, w = tid >> 6, lane = tid & 63;                  \
  const int ml = lane & 15, quad = lane >> 4;                                  \
  const int m0 = blockIdx.y * 128, n0 = blockIdx.x * 128;                      \
  const int wm = w & 1, wn = w >> 1;                                           \
  const int srow = lane >> 3;                 /* 0..7 within 8-row slab */     \
  const int scol = ((lane & 7) ^ srow) * 8;   /* swizzled global chunk */      \
  f32x4 acc[4][4];                                                             \
  _Pragma("unroll") for (int mi = 0; mi < 4; mi++)                             \
    _Pragma("unroll") for (int ni = 0; ni < 4; ni++)                           \
      _Pragma("unroll") for (int e = 0; e < 4; e++) acc[mi][ni][e] = 0.f;      \
  for (int k0 = 0; k0 < DM; k0 += 64) {                                        \
    __syncthreads();                                                           \
    _Pragma("unroll") for (int L = 0; L < 4; L++) {                            \
      int I = w * 4 + L;                                                       \
      gl_lds16(Aptr  + (size_t)(m0 + I * 8 + srow) * DM + k0 + scol,           \
               As + I * 512);                                                  \
      gl_lds16(Btptr + (size_t)(n0 + I * 8 + srow) * DM + k0 + scol,           \
               Bs + I * 512);                                                  \
    }                                                                          \
    __syncthreads();                                                           \
    _Pragma("unroll") for (int kk = 0; kk < 64; kk += 32) {                    \
      const int kc = kk >> 3;                 /* chunk base: 0 or 4 */         \
      short8 am[4], bn[4];                                                     \
      _Pragma("unroll") for (int i = 0; i < 4; i++) {                          \
        int ra = wm * 64 + i * 16 + ml;                                        \
        int rb = wn * 64 + i * 16 + ml;                                        \
        am[i] = *(const short8*)&As[ra * 64 + (((quad + kc) ^ (ra & 7)) * 8)]; \
        bn[i] = *(const short8*)&Bs[rb * 64 + (((quad + kc) ^ (rb & 7)) * 8)]; \
      }                                                                        \
      _Pragma("unroll") for (int mi = 0; mi < 4; mi++)                         \
        _Pragma("unroll") for (int ni = 0; ni < 4; ni++)                       \
          acc[mi][ni] = __builtin_amdgcn_mfma_f32_16x16x32_bf16(               \
              am[mi], bn[ni], acc[mi][ni], 0, 0, 0);                           \
    }                                                                          \
  }

// ---------------------------------------------------------------------------
// QKV GEMM + fused L2 norm: Xb[4096][1024] bf16 @ W. z selects Q/K/V.
// Q,K: per-(head,token) L2-normalized in-register (Q also x1/8), -> [B,H,N,DH].
// V -> transposed [B,H,DH,N] (packed 8B stores). grid (8, 32, 3), 256 thr.
// ---------------------------------------------------------------------------
__global__ __launch_bounds__(256) void gemm_qkv128(
    const u16* __restrict__ Xb, const u16* __restrict__ WT,
    u16* __restrict__ Qo, u16* __restrict__ Ko, u16* __restrict__ Vt) {
  const u16* Bt = WT + (size_t)blockIdx.z * DM * DM;
  GEMM128_MAINLOOP(Xb, Bt)
  const int z = blockIdx.z;
  if (z < 2) {
    u16* OutQK = (z == 0) ? Qo : Ko;
    const float qsc = (z == 0) ? 0.125f : 1.0f;     // fold softmax 1/sqrt(64)
    const int h = (n0 >> 6) + wn;                   // head of this wave's cols
    #pragma unroll
    for (int mi = 0; mi < 4; mi++) {
      int mrow0 = m0 + wm * 64 + mi * 16 + quad * 4;
      int b = mrow0 >> 11, tok0 = mrow0 & (NSEQ - 1);
      #pragma unroll
      for (int r = 0; r < 4; r++) {
        float ss = 0.f;
        #pragma unroll
        for (int ni = 0; ni < 4; ni++) ss += acc[mi][ni][r] * acc[mi][ni][r];
        ss += __shfl_xor(ss, 1, 64);
        ss += __shfl_xor(ss, 2, 64);
        ss += __shfl_xor(ss, 4, 64);
        ss += __shfl_xor(ss, 8, 64);    // sum over the 16 ml lanes (full row)
        float sc = qsc / (sqrtf(ss) + EPS_N);
        #pragma unroll
        for (int ni = 0; ni < 4; ni++)
          OutQK[((size_t)(b * NH + h) * NSEQ + tok0 + r) * DH + ni * 16 + ml] =
              f2bf(acc[mi][ni][r] * sc);
      }
    }
  } else {
    #pragma unroll
    for (int mi = 0; mi < 4; mi++) {
      int mrow0 = m0 + wm * 64 + mi * 16 + quad * 4;
      int b = mrow0 >> 11, tok0 = mrow0 & (NSEQ - 1);
      #pragma unroll
      for (int ni = 0; ni < 4; ni++) {
        int n = n0 + wn * 64 + ni * 16 + ml;
        int h = n >> 6, d = n & 63;
        u16x4 pk;
        #pragma unroll
        for (int r = 0; r < 4; r++) pk[r] = f2bf(acc[mi][ni][r]);
        *(u16x4*)&Vt[((size_t)(b * NH + h) * DH + d) * NSEQ + tok0] = pk;
      }
    }
  }
}

// ---------------------------------------------------------------------------
// Output projection: out = vhat[4096][1024] @ Wo + bo, fp32 out.
// grid (8, 32), 256 thr.
// ---------------------------------------------------------------------------
__global__ __launch_bounds__(256) void gemm_proj128(
    const u16* __restrict__ A, const u16* __restrict__ BtW,
    const float* __restrict__ bias, float* __restrict__ out) {
  GEMM128_MAINLOOP(A, BtW)
  #pragma unroll
  for (int ni = 0; ni < 4; ni++) {
    int n = n0 + wn * 64 + ni * 16 + ml;
    float bz = bias[n];
    #pragma unroll
    for (int mi = 0; mi < 4; mi++) {
      int mrow0 = m0 + wm * 64 + mi * 16 + quad * 4;
      #pragma unroll
      for (int r = 0; r < 4; r++)
        out[(size_t)(mrow0 + r) * DM + n] = acc[mi][ni][r] + bz;
    }
  }
}

// ---------------------------------------------------------------------------
// MFMA flash attention, causal, NO online max (|score|<=0.125 by L2 norm) ->
// O and l are ADDITIVE partials: split keys across waves, combine once/phase.
// Block = 32 q-rows/phase; pair {y, 63-y} -> exactly 33 tile-iters/block.
// Waves: wq = q-half (16 rows), wk = key-half (32 of 64 keys).
// Grid (bh=32, pair=32): XCD = flat%8 = bh%8 -> each XCD touches 4 heads' K/V
// (~2 MB, fits 4 MB L2). 256 thr.
//
// v2: NO K/V LDS staging. K and V^T are L2-resident per XCD; both MFMA
// B-fragments are 16B-contiguous in global layout, so load them straight
// from global (VMEM pipe was idle; LDS pipe + the 144B-row bank conflicts
// were the bottleneck: MfmaUtil 11.5%, 7.3M conflict cycles). This also
// removes BOTH per-tile __syncthreads — waves free-run, only the phase-end
// wk0/wk1 combine synchronizes. K frags are prefetched one tile ahead in
// registers. LDS use drops 32 KB -> ~14 KB; only the per-wave P round-trip
// (C->A layout transform) remains on the LDS pipe.
// ---------------------------------------------------------------------------
__global__ __launch_bounds__(256, 4) void flash_attn(
    const u16* __restrict__ Qb, const u16* __restrict__ Kb,
    const u16* __restrict__ Vt, u16* __restrict__ vhat) {
  const int tid = threadIdx.x, w = tid >> 6, lane = tid & 63;
  const int ml = lane & 15, quad = lane >> 4;
  const int wq = w & 1, wk = w >> 1;
  const int bh = blockIdx.x;                  // 0..31 (= b*NH + h)
  const int bb = bh >> 4, hb = bh & 15;
  const int pair = blockIdx.y;                // 0..31
  const u16* Qh = Qb + (size_t)bh * NSEQ * DH;
  const u16* Kh = Kb + (size_t)bh * NSEQ * DH;
  const u16* Vth = Vt + (size_t)bh * DH * NSEQ;

  __shared__ u16 Ps [4][16][40];   // per-wave P[q16][key32] (C->A transform)
  __shared__ float Os[2][16][66];  // wk0's partial O [wq][q][d]
  __shared__ float Ls[2][16];      // wk0's partial l [wq][q]

  for (int ph = 0; ph < 2; ph++) {
    const int qb32 = ph ? (63 - pair) : pair;
    const int q0 = qb32 * 32;
    const int ntiles = (qb32 >> 1) + 1;

    // Q A-frags for this wave's 16 rows: A[m=ml][k=quad*8+j]
    short8 aq[2];
    #pragma unroll
    for (int c = 0; c < 2; c++)
      aq[c] = *(const short8*)&Qh[(size_t)(q0 + wq * 16 + ml) * DH + c * 32 + quad * 8];

    f32x4 oacc[4];
    #pragma unroll
    for (int n = 0; n < 4; n++)
      #pragma unroll
      for (int e = 0; e < 4; e++) oacc[n][e] = 0.f;
    float l_[4] = {0.f, 0.f, 0.f, 0.f};

    // Per-lane global fragment pointers.
    // K B-frag: B[k=d][n=key] -> lane reads K[wk*32 + n*16 + ml][c*32+quad*8]
    //   one pointer, imm offsets {0,64,2048,2112}B; advance 64*DH elems/tile.
    // V B-frag: B[k=key][n=d] -> lane reads V^T[n*16+ml][wk*32+quad*8]
    //   4 pointers (row stride 16*NSEQ too big for imm); advance 64 elems/tile.
    const u16* kp  = Kh + (size_t)(wk * 32 + ml) * DH + quad * 8;
    const u16* vp0 = Vth + (size_t)ml * NSEQ + wk * 32 + quad * 8;
    const u16* vp1 = vp0 + (size_t)16 * NSEQ;
    const u16* vp2 = vp0 + (size_t)32 * NSEQ;
    const u16* vp3 = vp0 + (size_t)48 * NSEQ;

    // prefetch tile-0 K frags
    short8 kb[2][2];
    #pragma unroll
    for (int c = 0; c < 2; c++)
      #pragma unroll
      for (int n = 0; n < 2; n++)
        kb[c][n] = *(const short8*)&kp[n * 16 * DH + c * 32];

    for (int t = 0; t < ntiles; t++) {
      // V frags for THIS tile — issue early, consumed after exp/P phase
      short8 vb[4];
      vb[0] = *(const short8*)vp0; vp0 += 64;
      vb[1] = *(const short8*)vp1; vp1 += 64;
      vb[2] = *(const short8*)vp2; vp2 += 64;
      vb[3] = *(const short8*)vp3; vp3 += 64;

      // S (16q x 32k) from register K frags
      f32x4 sacc[2];
      #pragma unroll
      for (int n = 0; n < 2; n++)
        #pragma unroll
        for (int e = 0; e < 4; e++) sacc[n][e] = 0.f;
      #pragma unroll
      for (int c = 0; c < 2; c++)
        #pragma unroll
        for (int n = 0; n < 2; n++)
          sacc[n] = __builtin_amdgcn_mfma_f32_16x16x32_bf16(aq[c], kb[c][n], sacc[n], 0, 0, 0);

      // prefetch NEXT tile's K frags (regs dead after the S MFMAs above)
      kp += 64 * DH;
      if (t + 1 < ntiles) {
        #pragma unroll
        for (int c = 0; c < 2; c++)
          #pragma unroll
          for (int n = 0; n < 2; n++)
            kb[c][n] = *(const short8*)&kp[n * 16 * DH + c * 32];
      }

      // p = exp(s), causal-masked on the last tile. C-layout: col=ml(key),
      // row=quad*4+r (q).
      const bool lastt = (t == ntiles - 1);
      const int j0 = t * 64;
      float p[2][4];
      #pragma unroll
      for (int n = 0; n < 2; n++) {
        int j = j0 + wk * 32 + n * 16 + ml;
        #pragma unroll
        for (int r = 0; r < 4; r++) {
          int q = q0 + wq * 16 + quad * 4 + r;
          float e = __expf(sacc[n][r]);
          p[n][r] = (lastt && j > q) ? 0.f : e;
          l_[r] += p[n][r];
        }
      }

      // P -> per-wave LDS (C->A layout; same-wave ordering via lgkmcnt)
      #pragma unroll
      for (int n = 0; n < 2; n++)
        #pragma unroll
        for (int r = 0; r < 4; r++)
          Ps[w][quad * 4 + r][n * 16 + ml] = f2bf(p[n][r]);

      // O += P·V over this wave's 32 keys: A = P[q=ml][k=quad*8+j],
      // B = V^T[d = n*16+ml][key = wk*32 + quad*8+j] (vb, from global)
      short8 ap = *(const short8*)&Ps[w][ml][quad * 8];
      #pragma unroll
      for (int n = 0; n < 4; n++)
        oacc[n] = __builtin_amdgcn_mfma_f32_16x16x32_bf16(ap, vb[n], oacc[n], 0, 0, 0);
    }

    // combine the two key-halves (additive: no max rescaling exists)
    float lred[4];
    #pragma unroll
    for (int r = 0; r < 4; r++) {
      float lv = l_[r];
      lv += __shfl_xor(lv, 1, 64);
      lv += __shfl_xor(lv, 2, 64);
      lv += __shfl_xor(lv, 4, 64);
      lv += __shfl_xor(lv, 8, 64);
      lred[r] = lv;                 // per (quad,r): sum over this wave's keys
    }
    if (wk == 0) {
      #pragma unroll
      for (int n = 0; n < 4; n++)
        #pragma unroll
        for (int r = 0; r < 4; r++)
          Os[wq][quad * 4 + r][n * 16 + ml] = oacc[n][r];
      if (ml == 0) {
        #pragma unroll
        for (int r = 0; r < 4; r++) Ls[wq][quad * 4 + r] = lred[r];
      }
    }
    __syncthreads();
    if (wk == 1) {
      #pragma unroll
      for (int r = 0; r < 4; r++) {
        float inv = 1.f / (lred[r] + Ls[wq][quad * 4 + r]);
        int q = q0 + wq * 16 + quad * 4 + r;
        #pragma unroll
        for (int n = 0; n < 4; n++) {
          float o = oacc[n][r] + Os[wq][quad * 4 + r][n * 16 + ml];
          vhat[((size_t)(bb * NSEQ + q)) * DM + hb * DH + n * 16 + ml] =
              f2bf(o * inv);
        }
      }
    }
    // protect Os/Ls reuse by next phase's wk0 writes (the staging barriers
    // used to provide this ordering)
    __syncthreads();
  }
}

// ---------------------------------------------------------------------------
extern "C" void kernel_launch(void* const* d_in, const int* in_sizes, int n_in,
                              void* d_out, int out_size, void* d_ws, size_t ws_size,
                              hipStream_t stream) {
  const float* X  = (const float*)d_in[0];
  const float* Wq = (const float*)d_in[1];
  const float* Wk = (const float*)d_in[2];
  const float* Wv = (const float*)d_in[3];
  const float* Wo = (const float*)d_in[4];
  const float* bo = (const float*)d_in[5];
  float* out = (float*)d_out;

  // ws (all bf16, 8 MB each): Qb | Kb | Vt[B,H,DH,N] | {Xb then vhat, aliased}
  // | WT (4 transposed weights, 8 MB total) = 40 MB
  const size_t NE = (size_t)BATCH * NSEQ * DM;   // 4,194,304
  u16* Qb   = (u16*)d_ws;
  u16* Kb   = Qb + NE;
  u16* Vt   = Kb + NE;
  u16* XbVh = Vt + NE;                           // Xb / vhat (disjoint lifetimes)
  u16* WT   = XbVh + NE;

  prep        <<<dim3(3072),      256, 0, stream>>>(X, Wq, Wk, Wv, Wo, XbVh, WT);
  gemm_qkv128 <<<dim3(8, 32, 3),  256, 0, stream>>>(XbVh, WT, Qb, Kb, Vt);
  flash_attn  <<<dim3(32, 32),    256, 0, stream>>>(Qb, Kb, Vt, XbVh);
  gemm_proj128<<<dim3(8, 32, 1),  256, 0, stream>>>(XbVh, WT + 3 * (size_t)DM * DM,
                                                    bo, out);
}

// Round 3
// 201.104 us; speedup vs baseline: 1.3574x; 1.3574x over previous
//
#include <hip/hip_runtime.h>
#include <hip/hip_bf16.h>
#include <math.h>

// Problem: B=2, N=2048, D_MODEL=1024, H=16, D_HEAD=64. fp32 in/out,
// bf16 MFMA internal (threshold is bf16-grade: 2% of max|ref|).
#define BATCH 2
#define NSEQ  2048
#define DM    1024
#define NH    16
#define DH    64
#define EPS_N 1e-6f

typedef unsigned short u16;
typedef __attribute__((ext_vector_type(8))) short short8;       // bf16x8 MFMA frag
typedef __attribute__((ext_vector_type(8))) unsigned short u16x8;
typedef __attribute__((ext_vector_type(4))) unsigned short u16x4;
typedef __attribute__((ext_vector_type(4))) float f32x4;

__device__ __forceinline__ u16 f2bf(float x) {
  __hip_bfloat16 h = __float2bfloat16(x);          // round-to-nearest-even
  return *reinterpret_cast<u16*>(&h);
}

// async 16B global->LDS (lane i lands at lds_base + 16*i)
__device__ __forceinline__ void gl_lds16(const u16* g, u16* lds_base) {
  __builtin_amdgcn_global_load_lds(
      (__attribute__((address_space(1))) void*)g,
      (__attribute__((address_space(3))) void*)lds_base, 16, 0, 0);
}

// ---------------------------------------------------------------------------
// Prep: blocks 0..1023 transpose+cast the 4 weight matrices (out[n][k] =
// bf16(in[k][n])); blocks 1024..3071 cast X fp32->bf16. grid 3072, 256 thr.
// ---------------------------------------------------------------------------
__global__ __launch_bounds__(256) void prep(
    const float* __restrict__ X,
    const float* __restrict__ w0, const float* __restrict__ w1,
    const float* __restrict__ w2, const float* __restrict__ w3,
    u16* __restrict__ Xb, u16* __restrict__ WT) {
  const int id = blockIdx.x, tid = threadIdx.x;
  if (id >= 1024) {                       // ---- cast X chunk
    size_t base = ((size_t)(id - 1024) * 256 + tid) * 8;
    float4 f0 = *(const float4*)&X[base];
    float4 f1 = *(const float4*)&X[base + 4];
    u16x8 v;
    v[0] = f2bf(f0.x); v[1] = f2bf(f0.y); v[2] = f2bf(f0.z); v[3] = f2bf(f0.w);
    v[4] = f2bf(f1.x); v[5] = f2bf(f1.y); v[6] = f2bf(f1.z); v[7] = f2bf(f1.w);
    *(u16x8*)&Xb[base] = v;
    return;
  }
  // ---- weight transpose tile
  const int z = id >> 8, xy = id & 255, bx = xy & 15, by = xy >> 4;
  const float* in = (z == 0) ? w0 : (z == 1) ? w1 : (z == 2) ? w2 : w3;
  u16* o = WT + (size_t)z * DM * DM;
  __shared__ u16 T[64][65];
  const int n0 = bx * 64, k0 = by * 64;
  #pragma unroll
  for (int i = 0; i < 4; i++) {
    int c = tid + 256 * i, row = c >> 4, col4 = c & 15;
    float4 f = *(const float4*)&in[(size_t)(k0 + row) * DM + n0 + col4 * 4];
    T[row][col4 * 4 + 0] = f2bf(f.x);
    T[row][col4 * 4 + 1] = f2bf(f.y);
    T[row][col4 * 4 + 2] = f2bf(f.z);
    T[row][col4 * 4 + 3] = f2bf(f.w);
  }
  __syncthreads();
  #pragma unroll
  for (int i = 0; i < 2; i++) {
    int c = tid + 256 * i, row = c >> 3, col8 = c & 7;
    u16x8 v;
    #pragma unroll
    for (int e = 0; e < 8; e++) v[e] = T[col8 * 8 + e][row];
    *(u16x8*)&o[(size_t)(n0 + row) * DM + k0 + col8 * 8] = v;
  }
}

// ===========================================================================
// m97-style 128x128 GEMM mainloop (BK=64, global_load_lds 16B, XOR-swizzled
// LDS chunks). A[m][k], Bt[n][k] both bf16. 256 thr, 4 waves in 2x2 (wm,wn).
// LDS: row r (128 B) holds global chunk g at position g^(r&7).
// ===========================================================================
#define GEMM128_MAINLOOP(Aptr, Btptr)                                          \
  __shared__ u16 As[128 * 64];                                                 \
  __shared__ u16 Bs[128 * 64];                                                 \
  const int tid = threadIdx.x, w = tid >> 6, lane = tid & 63;                  \
  const int ml = lane & 15, quad = lane >> 4;                                  \
  const int m0 = blockIdx.y * 128, n0 = blockIdx.x * 128;                      \
  const int wm = w & 1, wn = w >> 1;                                           \
  const int srow = lane >> 3;                 /* 0..7 within 8-row slab */     \
  const int scol = ((lane & 7) ^ srow) * 8;   /* swizzled global chunk */      \
  f32x4 acc[4][4];                                                             \
  _Pragma("unroll") for (int mi = 0; mi < 4; mi++)                             \
    _Pragma("unroll") for (int ni = 0; ni < 4; ni++)                           \
      _Pragma("unroll") for (int e = 0; e < 4; e++) acc[mi][ni][e] = 0.f;      \
  for (int k0 = 0; k0 < DM; k0 += 64) {                                        \
    __syncthreads();                                                           \
    _Pragma("unroll") for (int L = 0; L < 4; L++) {                            \
      int I = w * 4 + L;                                                       \
      gl_lds16(Aptr  + (size_t)(m0 + I * 8 + srow) * DM + k0 + scol,           \
               As + I * 512);                                                  \
      gl_lds16(Btptr + (size_t)(n0 + I * 8 + srow) * DM + k0 + scol,           \
               Bs + I * 512);                                                  \
    }                                                                          \
    __syncthreads();                                                           \
    _Pragma("unroll") for (int kk = 0; kk < 64; kk += 32) {                    \
      const int kc = kk >> 3;                 /* chunk base: 0 or 4 */         \
      short8 am[4], bn[4];                                                     \
      _Pragma("unroll") for (int i = 0; i < 4; i++) {                          \
        int ra = wm * 64 + i * 16 + ml;                                        \
        int rb = wn * 64 + i * 16 + ml;                                        \
        am[i] = *(const short8*)&As[ra * 64 + (((quad + kc) ^ (ra & 7)) * 8)]; \
        bn[i] = *(const short8*)&Bs[rb * 64 + (((quad + kc) ^ (rb & 7)) * 8)]; \
      }                                                                        \
      _Pragma("unroll") for (int mi = 0; mi < 4; mi++)                         \
        _Pragma("unroll") for (int ni = 0; ni < 4; ni++)                       \
          acc[mi][ni] = __builtin_amdgcn_mfma_f32_16x16x32_bf16(               \
              am[mi], bn[ni], acc[mi][ni], 0, 0, 0);                           \
    }                                                                          \
  }

// ---------------------------------------------------------------------------
// QKV GEMM + fused L2 norm: Xb[4096][1024] bf16 @ W. z selects Q/K/V.
// Q,K: per-(head,token) L2-normalized in-register (Q also x1/8), -> [B,H,N,DH].
// V -> transposed [B,H,DH,N] (packed 8B stores). grid (8, 32, 3), 256 thr.
// ---------------------------------------------------------------------------
__global__ __launch_bounds__(256) void gemm_qkv128(
    const u16* __restrict__ Xb, const u16* __restrict__ WT,
    u16* __restrict__ Qo, u16* __restrict__ Ko, u16* __restrict__ Vt) {
  const u16* Bt = WT + (size_t)blockIdx.z * DM * DM;
  GEMM128_MAINLOOP(Xb, Bt)
  const int z = blockIdx.z;
  if (z < 2) {
    u16* OutQK = (z == 0) ? Qo : Ko;
    const float qsc = (z == 0) ? 0.125f : 1.0f;     // fold softmax 1/sqrt(64)
    const int h = (n0 >> 6) + wn;                   // head of this wave's cols
    #pragma unroll
    for (int mi = 0; mi < 4; mi++) {
      int mrow0 = m0 + wm * 64 + mi * 16 + quad * 4;
      int b = mrow0 >> 11, tok0 = mrow0 & (NSEQ - 1);
      #pragma unroll
      for (int r = 0; r < 4; r++) {
        float ss = 0.f;
        #pragma unroll
        for (int ni = 0; ni < 4; ni++) ss += acc[mi][ni][r] * acc[mi][ni][r];
        ss += __shfl_xor(ss, 1, 64);
        ss += __shfl_xor(ss, 2, 64);
        ss += __shfl_xor(ss, 4, 64);
        ss += __shfl_xor(ss, 8, 64);    // sum over the 16 ml lanes (full row)
        float sc = qsc / (sqrtf(ss) + EPS_N);
        #pragma unroll
        for (int ni = 0; ni < 4; ni++)
          OutQK[((size_t)(b * NH + h) * NSEQ + tok0 + r) * DH + ni * 16 + ml] =
              f2bf(acc[mi][ni][r] * sc);
      }
    }
  } else {
    #pragma unroll
    for (int mi = 0; mi < 4; mi++) {
      int mrow0 = m0 + wm * 64 + mi * 16 + quad * 4;
      int b = mrow0 >> 11, tok0 = mrow0 & (NSEQ - 1);
      #pragma unroll
      for (int ni = 0; ni < 4; ni++) {
        int n = n0 + wn * 64 + ni * 16 + ml;
        int h = n >> 6, d = n & 63;
        u16x4 pk;
        #pragma unroll
        for (int r = 0; r < 4; r++) pk[r] = f2bf(acc[mi][ni][r]);
        *(u16x4*)&Vt[((size_t)(b * NH + h) * DH + d) * NSEQ + tok0] = pk;
      }
    }
  }
}

// ---------------------------------------------------------------------------
// Output projection: out = vhat[4096][1024] @ Wo + bo, fp32 out.
// grid (8, 32), 256 thr.
// ---------------------------------------------------------------------------
__global__ __launch_bounds__(256) void gemm_proj128(
    const u16* __restrict__ A, const u16* __restrict__ BtW,
    const float* __restrict__ bias, float* __restrict__ out) {
  GEMM128_MAINLOOP(A, BtW)
  #pragma unroll
  for (int ni = 0; ni < 4; ni++) {
    int n = n0 + wn * 64 + ni * 16 + ml;
    float bz = bias[n];
    #pragma unroll
    for (int mi = 0; mi < 4; mi++) {
      int mrow0 = m0 + wm * 64 + mi * 16 + quad * 4;
      #pragma unroll
      for (int r = 0; r < 4; r++)
        out[(size_t)(mrow0 + r) * DM + n] = acc[mi][ni][r] + bz;
    }
  }
}

// ---------------------------------------------------------------------------
// MFMA flash attention, causal, NO online max (|score|<=0.125 by L2 norm) ->
// O and l are ADDITIVE partials: split keys across waves, combine once/phase.
// Block = 32 q-rows/phase; pair {y, 63-y} -> exactly 33 tile-iters/block.
// Waves: wq = q-half (16 rows), wk = key-half (32 of 64 keys).
// Grid (bh=32, pair=32): XCD = flat%8 = bh%8 -> each XCD touches 4 heads' K/V
// (~2 MB, fits 4 MB L2). 256 thr.
//
// v3: back to v1's staged-LDS structure (v2's global-direct frags removed the
// latency-hiding pipeline: 126 us, MfmaUtil 5.4%). Fix v1's measured defect
// instead: 7.29M bank-conflict cycles from the 144B-row [64][72] staging
// layout. K/V now stage into LINEAR [64][64] tiles via global_load_lds with
// a pre-swizzled global source (chunk g of row r lands at position g^(r&7));
// frag reads XOR the chunk index with (row&7). Writes conflict-free by
// construction, reads <=2-way (free). Bonus: no staging VGPRs, LDS 32.25 ->
// 29.4 KB -> 5 blocks/CU (20 waves) instead of 4.
// ---------------------------------------------------------------------------
__global__ __launch_bounds__(256) void flash_attn(
    const u16* __restrict__ Qb, const u16* __restrict__ Kb,
    const u16* __restrict__ Vt, u16* __restrict__ vhat) {
  const int tid = threadIdx.x, w = tid >> 6, lane = tid & 63;
  const int ml = lane & 15, quad = lane >> 4;
  const int wq = w & 1, wk = w >> 1;
  const int bh = blockIdx.x;                  // 0..31 (= b*NH + h)
  const int bb = bh >> 4, hb = bh & 15;
  const int pair = blockIdx.y;                // 0..31
  const u16* Qh = Qb + (size_t)bh * NSEQ * DH;
  const u16* Kh = Kb + (size_t)bh * NSEQ * DH;
  const u16* Vth = Vt + (size_t)bh * DH * NSEQ;

  __shared__ u16 Ks [64 * 64];     // K[key][d], linear rows, chunks swizzled
  __shared__ u16 VsT[64 * 64];     // V^T[d][key], same scheme
  __shared__ u16 Ps [4][16][40];   // per-wave P[q16][key32] (C->A transform)
  __shared__ float Os[2][16][66];  // wk0's partial O [wq][q][d]
  __shared__ float Ls[2][16];      // wk0's partial l [wq][q]

  // staging source swizzle: one gl_lds16 covers 8 rows x 8 chunks (1 KB).
  // lane -> LDS slot (row srow8, pos lane&7); fetch global chunk pos^(srow8&7)
  const int srow8  = lane >> 3;               // 0..7 row within slab
  const int schunk = (lane & 7) ^ srow8;      // global chunk for this slot

  for (int ph = 0; ph < 2; ph++) {
    const int qb32 = ph ? (63 - pair) : pair;
    const int q0 = qb32 * 32;
    const int ntiles = (qb32 >> 1) + 1;

    // Q A-frags for this wave's 16 rows: A[m=ml][k=quad*8+j]
    short8 aq[2];
    #pragma unroll
    for (int c = 0; c < 2; c++)
      aq[c] = *(const short8*)&Qh[(size_t)(q0 + wq * 16 + ml) * DH + c * 32 + quad * 8];

    f32x4 oacc[4];
    #pragma unroll
    for (int n = 0; n < 4; n++)
      #pragma unroll
      for (int e = 0; e < 4; e++) oacc[n][e] = 0.f;
    float l_[4] = {0.f, 0.f, 0.f, 0.f};

    for (int t = 0; t < ntiles; t++) {
      const int j0 = t * 64;
      __syncthreads();                       // all waves done with prev tile
      // stage K tile (rows=keys) and V^T tile (rows=d); wave w covers slabs
      // w*2, w*2+1 of each (8 rows/slab).
      #pragma unroll
      for (int i = 0; i < 2; i++) {
        int slab = w * 2 + i;
        gl_lds16(Kh  + (size_t)(j0 + slab * 8 + srow8) * DH + schunk * 8,
                 Ks + slab * 512);
        gl_lds16(Vth + (size_t)(slab * 8 + srow8) * NSEQ + j0 + schunk * 8,
                 VsT + slab * 512);
      }
      __syncthreads();                       // drains vmcnt -> tiles ready

      // S (16q x 32k): B-frag = K[key = wk*32 + n*16+ml][d = c*32+quad*8+j]
      f32x4 sacc[2];
      #pragma unroll
      for (int n = 0; n < 2; n++)
        #pragma unroll
        for (int e = 0; e < 4; e++) sacc[n][e] = 0.f;
      #pragma unroll
      for (int c = 0; c < 2; c++)
        #pragma unroll
        for (int n = 0; n < 2; n++) {
          int kr = wk * 32 + n * 16 + ml;
          short8 bf = *(const short8*)&Ks[kr * 64 + (((c * 4 + quad) ^ (kr & 7)) * 8)];
          sacc[n] = __builtin_amdgcn_mfma_f32_16x16x32_bf16(aq[c], bf, sacc[n], 0, 0, 0);
        }

      // p = exp(s), causal-masked on the last tile. C-layout: col=ml(key),
      // row=quad*4+r (q).
      const bool lastt = (t == ntiles - 1);
      float p[2][4];
      #pragma unroll
      for (int n = 0; n < 2; n++) {
        int j = j0 + wk * 32 + n * 16 + ml;
        #pragma unroll
        for (int r = 0; r < 4; r++) {
          int q = q0 + wq * 16 + quad * 4 + r;
          float e = __expf(sacc[n][r]);
          p[n][r] = (lastt && j > q) ? 0.f : e;
          l_[r] += p[n][r];
        }
      }

      // P -> per-wave LDS (C->A layout; same-wave ordering via lgkmcnt)
      #pragma unroll
      for (int n = 0; n < 2; n++)
        #pragma unroll
        for (int r = 0; r < 4; r++)
          Ps[w][quad * 4 + r][n * 16 + ml] = f2bf(p[n][r]);

      // O += P·V over this wave's 32 keys: A = P[q=ml][k=quad*8+j],
      // B = V^T[d = n*16+ml][key = wk*32 + quad*8+j]
      short8 ap = *(const short8*)&Ps[w][ml][quad * 8];
      #pragma unroll
      for (int n = 0; n < 4; n++) {
        int dr = n * 16 + ml;
        short8 bv = *(const short8*)&VsT[dr * 64 + (((wk * 4 + quad) ^ (dr & 7)) * 8)];
        oacc[n] = __builtin_amdgcn_mfma_f32_16x16x32_bf16(ap, bv, oacc[n], 0, 0, 0);
      }
    }

    // combine the two key-halves (additive: no max rescaling exists)
    float lred[4];
    #pragma unroll
    for (int r = 0; r < 4; r++) {
      float lv = l_[r];
      lv += __shfl_xor(lv, 1, 64);
      lv += __shfl_xor(lv, 2, 64);
      lv += __shfl_xor(lv, 4, 64);
      lv += __shfl_xor(lv, 8, 64);
      lred[r] = lv;                 // per (quad,r): sum over this wave's keys
    }
    if (wk == 0) {
      #pragma unroll
      for (int n = 0; n < 4; n++)
        #pragma unroll
        for (int r = 0; r < 4; r++)
          Os[wq][quad * 4 + r][n * 16 + ml] = oacc[n][r];
      if (ml == 0) {
        #pragma unroll
        for (int r = 0; r < 4; r++) Ls[wq][quad * 4 + r] = lred[r];
      }
    }
    __syncthreads();
    if (wk == 1) {
      #pragma unroll
      for (int r = 0; r < 4; r++) {
        float inv = 1.f / (lred[r] + Ls[wq][quad * 4 + r]);
        int q = q0 + wq * 16 + quad * 4 + r;
        #pragma unroll
        for (int n = 0; n < 4; n++) {
          float o = oacc[n][r] + Os[wq][quad * 4 + r][n * 16 + ml];
          vhat[((size_t)(bb * NSEQ + q)) * DM + hb * DH + n * 16 + ml] =
              f2bf(o * inv);
        }
      }
    }
    // protect Os/Ls (and Ks/VsT) reuse by the next phase
    __syncthreads();
  }
}

// ---------------------------------------------------------------------------
extern "C" void kernel_launch(void* const* d_in, const int* in_sizes, int n_in,
                              void* d_out, int out_size, void* d_ws, size_t ws_size,
                              hipStream_t stream) {
  const float* X  = (const float*)d_in[0];
  const float* Wq = (const float*)d_in[1];
  const float* Wk = (const float*)d_in[2];
  const float* Wv = (const float*)d_in[3];
  const float* Wo = (const float*)d_in[4];
  const float* bo = (const float*)d_in[5];
  float* out = (float*)d_out;

  // ws (all bf16, 8 MB each): Qb | Kb | Vt[B,H,DH,N] | {Xb then vhat, aliased}
  // | WT (4 transposed weights, 8 MB total) = 40 MB
  const size_t NE = (size_t)BATCH * NSEQ * DM;   // 4,194,304
  u16* Qb   = (u16*)d_ws;
  u16* Kb   = Qb + NE;
  u16* Vt   = Kb + NE;
  u16* XbVh = Vt + NE;                           // Xb / vhat (disjoint lifetimes)
  u16* WT   = XbVh + NE;

  prep        <<<dim3(3072),      256, 0, stream>>>(X, Wq, Wk, Wv, Wo, XbVh, WT);
  gemm_qkv128 <<<dim3(8, 32, 3),  256, 0, stream>>>(XbVh, WT, Qb, Kb, Vt);
  flash_attn  <<<dim3(32, 32),    256, 0, stream>>>(Qb, Kb, Vt, XbVh);
  gemm_proj128<<<dim3(8, 32, 1),  256, 0, stream>>>(XbVh, WT + 3 * (size_t)DM * DM,
                                                    bo, out);
}

// Round 4
// 200.386 us; speedup vs baseline: 1.3623x; 1.0036x over previous
//
#include <hip/hip_runtime.h>
#include <hip/hip_bf16.h>
#include <math.h>

// Problem: B=2, N=2048, D_MODEL=1024, H=16, D_HEAD=64. fp32 in/out,
// bf16 MFMA internal (threshold is bf16-grade: 2% of max|ref|).
#define BATCH 2
#define NSEQ  2048
#define DM    1024
#define NH    16
#define DH    64
#define EPS_N 1e-6f

typedef unsigned short u16;
typedef __attribute__((ext_vector_type(8))) short short8;       // bf16x8 MFMA frag
typedef __attribute__((ext_vector_type(8))) unsigned short u16x8;
typedef __attribute__((ext_vector_type(4))) unsigned short u16x4;
typedef __attribute__((ext_vector_type(4))) float f32x4;

__device__ __forceinline__ u16 f2bf(float x) {
  __hip_bfloat16 h = __float2bfloat16(x);          // round-to-nearest-even
  return *reinterpret_cast<u16*>(&h);
}

// async 16B global->LDS (lane i lands at lds_base + 16*i)
__device__ __forceinline__ void gl_lds16(const u16* g, u16* lds_base) {
  __builtin_amdgcn_global_load_lds(
      (__attribute__((address_space(1))) void*)g,
      (__attribute__((address_space(3))) void*)lds_base, 16, 0, 0);
}

// ---------------------------------------------------------------------------
// Prep: blocks 0..1023 transpose+cast the 4 weight matrices (out[n][k] =
// bf16(in[k][n])); blocks 1024..3071 cast X fp32->bf16. grid 3072, 256 thr.
// ---------------------------------------------------------------------------
__global__ __launch_bounds__(256) void prep(
    const float* __restrict__ X,
    const float* __restrict__ w0, const float* __restrict__ w1,
    const float* __restrict__ w2, const float* __restrict__ w3,
    u16* __restrict__ Xb, u16* __restrict__ WT) {
  const int id = blockIdx.x, tid = threadIdx.x;
  if (id >= 1024) {                       // ---- cast X chunk
    size_t base = ((size_t)(id - 1024) * 256 + tid) * 8;
    float4 f0 = *(const float4*)&X[base];
    float4 f1 = *(const float4*)&X[base + 4];
    u16x8 v;
    v[0] = f2bf(f0.x); v[1] = f2bf(f0.y); v[2] = f2bf(f0.z); v[3] = f2bf(f0.w);
    v[4] = f2bf(f1.x); v[5] = f2bf(f1.y); v[6] = f2bf(f1.z); v[7] = f2bf(f1.w);
    *(u16x8*)&Xb[base] = v;
    return;
  }
  // ---- weight transpose tile
  const int z = id >> 8, xy = id & 255, bx = xy & 15, by = xy >> 4;
  const float* in = (z == 0) ? w0 : (z == 1) ? w1 : (z == 2) ? w2 : w3;
  u16* o = WT + (size_t)z * DM * DM;
  __shared__ u16 T[64][65];
  const int n0 = bx * 64, k0 = by * 64;
  #pragma unroll
  for (int i = 0; i < 4; i++) {
    int c = tid + 256 * i, row = c >> 4, col4 = c & 15;
    float4 f = *(const float4*)&in[(size_t)(k0 + row) * DM + n0 + col4 * 4];
    T[row][col4 * 4 + 0] = f2bf(f.x);
    T[row][col4 * 4 + 1] = f2bf(f.y);
    T[row][col4 * 4 + 2] = f2bf(f.z);
    T[row][col4 * 4 + 3] = f2bf(f.w);
  }
  __syncthreads();
  #pragma unroll
  for (int i = 0; i < 2; i++) {
    int c = tid + 256 * i, row = c >> 3, col8 = c & 7;
    u16x8 v;
    #pragma unroll
    for (int e = 0; e < 8; e++) v[e] = T[col8 * 8 + e][row];
    *(u16x8*)&o[(size_t)(n0 + row) * DM + k0 + col8 * 8] = v;
  }
}

// ===========================================================================
// m97-style 128x128 GEMM mainloop (BK=64, global_load_lds 16B, XOR-swizzled
// LDS chunks). A[m][k], Bt[n][k] both bf16. 256 thr, 4 waves in 2x2 (wm,wn).
// LDS: row r (128 B) holds global chunk g at position g^(r&7).
// ===========================================================================
#define GEMM128_MAINLOOP(Aptr, Btptr)                                          \
  __shared__ u16 As[128 * 64];                                                 \
  __shared__ u16 Bs[128 * 64];                                                 \
  const int tid = threadIdx.x, w = tid >> 6, lane = tid & 63;                  \
  const int ml = lane & 15, quad = lane >> 4;                                  \
  const int m0 = blockIdx.y * 128, n0 = blockIdx.x * 128;                      \
  const int wm = w & 1, wn = w >> 1;                                           \
  const int srow = lane >> 3;                 /* 0..7 within 8-row slab */     \
  const int scol = ((lane & 7) ^ srow) * 8;   /* swizzled global chunk */      \
  f32x4 acc[4][4];                                                             \
  _Pragma("unroll") for (int mi = 0; mi < 4; mi++)                             \
    _Pragma("unroll") for (int ni = 0; ni < 4; ni++)                           \
      _Pragma("unroll") for (int e = 0; e < 4; e++) acc[mi][ni][e] = 0.f;      \
  for (int k0 = 0; k0 < DM; k0 += 64) {                                        \
    __syncthreads();                                                           \
    _Pragma("unroll") for (int L = 0; L < 4; L++) {                            \
      int I = w * 4 + L;                                                       \
      gl_lds16(Aptr  + (size_t)(m0 + I * 8 + srow) * DM + k0 + scol,           \
               As + I * 512);                                                  \
      gl_lds16(Btptr + (size_t)(n0 + I * 8 + srow) * DM + k0 + scol,           \
               Bs + I * 512);                                                  \
    }                                                                          \
    __syncthreads();                                                           \
    _Pragma("unroll") for (int kk = 0; kk < 64; kk += 32) {                    \
      const int kc = kk >> 3;                 /* chunk base: 0 or 4 */         \
      short8 am[4], bn[4];                                                     \
      _Pragma("unroll") for (int i = 0; i < 4; i++) {                          \
        int ra = wm * 64 + i * 16 + ml;                                        \
        int rb = wn * 64 + i * 16 + ml;                                        \
        am[i] = *(const short8*)&As[ra * 64 + (((quad + kc) ^ (ra & 7)) * 8)]; \
        bn[i] = *(const short8*)&Bs[rb * 64 + (((quad + kc) ^ (rb & 7)) * 8)]; \
      }                                                                        \
      _Pragma("unroll") for (int mi = 0; mi < 4; mi++)                         \
        _Pragma("unroll") for (int ni = 0; ni < 4; ni++)                       \
          acc[mi][ni] = __builtin_amdgcn_mfma_f32_16x16x32_bf16(               \
              am[mi], bn[ni], acc[mi][ni], 0, 0, 0);                           \
    }                                                                          \
  }

// ---------------------------------------------------------------------------
// QKV GEMM + fused L2 norm: Xb[4096][1024] bf16 @ W. z selects Q/K/V.
// Q,K: per-(head,token) L2-normalized in-register (Q also x1/8), -> [B,H,N,DH].
// V -> transposed [B,H,DH,N] (packed 8B stores). grid (8, 32, 3), 256 thr.
// ---------------------------------------------------------------------------
__global__ __launch_bounds__(256) void gemm_qkv128(
    const u16* __restrict__ Xb, const u16* __restrict__ WT,
    u16* __restrict__ Qo, u16* __restrict__ Ko, u16* __restrict__ Vt) {
  const u16* Bt = WT + (size_t)blockIdx.z * DM * DM;
  GEMM128_MAINLOOP(Xb, Bt)
  const int z = blockIdx.z;
  if (z < 2) {
    u16* OutQK = (z == 0) ? Qo : Ko;
    const float qsc = (z == 0) ? 0.125f : 1.0f;     // fold softmax 1/sqrt(64)
    const int h = (n0 >> 6) + wn;                   // head of this wave's cols
    #pragma unroll
    for (int mi = 0; mi < 4; mi++) {
      int mrow0 = m0 + wm * 64 + mi * 16 + quad * 4;
      int b = mrow0 >> 11, tok0 = mrow0 & (NSEQ - 1);
      #pragma unroll
      for (int r = 0; r < 4; r++) {
        float ss = 0.f;
        #pragma unroll
        for (int ni = 0; ni < 4; ni++) ss += acc[mi][ni][r] * acc[mi][ni][r];
        ss += __shfl_xor(ss, 1, 64);
        ss += __shfl_xor(ss, 2, 64);
        ss += __shfl_xor(ss, 4, 64);
        ss += __shfl_xor(ss, 8, 64);    // sum over the 16 ml lanes (full row)
        float sc = qsc / (sqrtf(ss) + EPS_N);
        #pragma unroll
        for (int ni = 0; ni < 4; ni++)
          OutQK[((size_t)(b * NH + h) * NSEQ + tok0 + r) * DH + ni * 16 + ml] =
              f2bf(acc[mi][ni][r] * sc);
      }
    }
  } else {
    #pragma unroll
    for (int mi = 0; mi < 4; mi++) {
      int mrow0 = m0 + wm * 64 + mi * 16 + quad * 4;
      int b = mrow0 >> 11, tok0 = mrow0 & (NSEQ - 1);
      #pragma unroll
      for (int ni = 0; ni < 4; ni++) {
        int n = n0 + wn * 64 + ni * 16 + ml;
        int h = n >> 6, d = n & 63;
        u16x4 pk;
        #pragma unroll
        for (int r = 0; r < 4; r++) pk[r] = f2bf(acc[mi][ni][r]);
        *(u16x4*)&Vt[((size_t)(b * NH + h) * DH + d) * NSEQ + tok0] = pk;
      }
    }
  }
}

// ---------------------------------------------------------------------------
// Output projection: out = vhat[4096][1024] @ Wo + bo, fp32 out.
// grid (8, 32), 256 thr.
// ---------------------------------------------------------------------------
__global__ __launch_bounds__(256) void gemm_proj128(
    const u16* __restrict__ A, const u16* __restrict__ BtW,
    const float* __restrict__ bias, float* __restrict__ out) {
  GEMM128_MAINLOOP(A, BtW)
  #pragma unroll
  for (int ni = 0; ni < 4; ni++) {
    int n = n0 + wn * 64 + ni * 16 + ml;
    float bz = bias[n];
    #pragma unroll
    for (int mi = 0; mi < 4; mi++) {
      int mrow0 = m0 + wm * 64 + mi * 16 + quad * 4;
      #pragma unroll
      for (int r = 0; r < 4; r++)
        out[(size_t)(mrow0 + r) * DM + n] = acc[mi][ni][r] + bz;
    }
  }
}

// ---------------------------------------------------------------------------
// MFMA flash attention, causal, NO online max (|score|<=0.125 by L2 norm) ->
// O and l are ADDITIVE partials: split keys across waves, combine once/phase.
// Block = 32 q-rows/phase; pair {y, 63-y} -> exactly 33 tile-iters/block.
// Waves: wq = q-half (16 rows), wk = key-half (32 of 64 keys).
// Grid (bh=32, pair=32): XCD = flat%8 = bh%8 -> each XCD touches 4 heads' K/V
// (~2 MB, fits 4 MB L2). 256 thr.
//
// v4 = v3 + T14 async-STAGE split. v3's staging was issue->immediate
// vmcnt(0) drain at the barrier: every tile paid the full ~250cy L2 latency
// exposed (MfmaUtil stuck at 12.6%). Now each tile's K/V is loaded into
// REGISTERS one tile ahead (issued right after the LDS writes of the current
// tile, in flight during the whole compute), and written regs->LDS after the
// next barrier. ds_write is per-lane scatter, so the LDS dest carries the
// XOR swizzle directly (linear global read; LDS[r][slot s] = chunk s^r, same
// read-side XOR as v3). +16 VGPR, LDS unchanged 29.5 KB, 2 barriers/tile.
// ---------------------------------------------------------------------------
__global__ __launch_bounds__(256) void flash_attn(
    const u16* __restrict__ Qb, const u16* __restrict__ Kb,
    const u16* __restrict__ Vt, u16* __restrict__ vhat) {
  const int tid = threadIdx.x, w = tid >> 6, lane = tid & 63;
  const int ml = lane & 15, quad = lane >> 4;
  const int wq = w & 1, wk = w >> 1;
  const int bh = blockIdx.x;                  // 0..31 (= b*NH + h)
  const int bb = bh >> 4, hb = bh & 15;
  const int pair = blockIdx.y;                // 0..31
  const u16* Qh = Qb + (size_t)bh * NSEQ * DH;
  const u16* Kh = Kb + (size_t)bh * NSEQ * DH;
  const u16* Vth = Vt + (size_t)bh * DH * NSEQ;

  __shared__ u16 Ks [64 * 64];     // K[key][d], chunk s of row r = global s^r
  __shared__ u16 VsT[64 * 64];     // V^T[d][key], same scheme
  __shared__ u16 Ps [4][16][40];   // per-wave P[q16][key32] (C->A transform)
  __shared__ float Os[2][16][66];  // wk0's partial O [wq][q][d]
  __shared__ float Ls[2][16];      // wk0's partial l [wq][q]

  // staging geometry: wave w covers slabs {2w, 2w+1} (8 rows each) of both
  // tiles. lane -> row srow8 (within slab), LINEAR global chunk sch; the
  // ds_write lands at swizzled slot sch^srow8.
  const int srow8 = lane >> 3;                // 0..7 row within slab
  const int sch   = lane & 7;                 // linear global 16B chunk
  const int sslot = sch ^ srow8;              // swizzled LDS 16B slot

  for (int ph = 0; ph < 2; ph++) {
    const int qb32 = ph ? (63 - pair) : pair;
    const int q0 = qb32 * 32;
    const int ntiles = (qb32 >> 1) + 1;

    // Q A-frags for this wave's 16 rows: A[m=ml][k=quad*8+j]
    short8 aq[2];
    #pragma unroll
    for (int c = 0; c < 2; c++)
      aq[c] = *(const short8*)&Qh[(size_t)(q0 + wq * 16 + ml) * DH + c * 32 + quad * 8];

    f32x4 oacc[4];
    #pragma unroll
    for (int n = 0; n < 4; n++)
      #pragma unroll
      for (int e = 0; e < 4; e++) oacc[n][e] = 0.f;
    float l_[4] = {0.f, 0.f, 0.f, 0.f};

    // prologue: prefetch tile 0's K/V into regs (drained at first barrier)
    u16x8 kreg[2], vreg[2];
    #pragma unroll
    for (int i = 0; i < 2; i++) {
      int slab = w * 2 + i;
      kreg[i] = *(const u16x8*)&Kh[(size_t)(slab * 8 + srow8) * DH + sch * 8];
      vreg[i] = *(const u16x8*)&Vth[(size_t)(slab * 8 + srow8) * NSEQ + sch * 8];
    }

    for (int t = 0; t < ntiles; t++) {
      const int j0 = t * 64;
      __syncthreads();            // A: all waves done with prev tile's LDS;
                                  //    implicit vmcnt(0) = this tile's regs ok
      #pragma unroll
      for (int i = 0; i < 2; i++) {
        int slab = w * 2 + i;
        *(u16x8*)&Ks [(slab * 8 + srow8) * 64 + sslot * 8] = kreg[i];
        *(u16x8*)&VsT[(slab * 8 + srow8) * 64 + sslot * 8] = vreg[i];
      }
      __syncthreads();            // B: staged tiles visible to all waves

      // prefetch NEXT tile into regs — in flight during this tile's compute
      if (t + 1 < ntiles) {
        const int j1 = j0 + 64;
        #pragma unroll
        for (int i = 0; i < 2; i++) {
          int slab = w * 2 + i;
          kreg[i] = *(const u16x8*)&Kh[(size_t)(j1 + slab * 8 + srow8) * DH + sch * 8];
          vreg[i] = *(const u16x8*)&Vth[(size_t)(slab * 8 + srow8) * NSEQ + j1 + sch * 8];
        }
      }

      // S (16q x 32k): B-frag = K[key = wk*32 + n*16+ml][d = c*32+quad*8+j]
      f32x4 sacc[2];
      #pragma unroll
      for (int n = 0; n < 2; n++)
        #pragma unroll
        for (int e = 0; e < 4; e++) sacc[n][e] = 0.f;
      #pragma unroll
      for (int c = 0; c < 2; c++)
        #pragma unroll
        for (int n = 0; n < 2; n++) {
          int kr = wk * 32 + n * 16 + ml;
          short8 bf = *(const short8*)&Ks[kr * 64 + (((c * 4 + quad) ^ (kr & 7)) * 8)];
          sacc[n] = __builtin_amdgcn_mfma_f32_16x16x32_bf16(aq[c], bf, sacc[n], 0, 0, 0);
        }

      // p = exp(s), causal-masked on the last tile. C-layout: col=ml(key),
      // row=quad*4+r (q).
      const bool lastt = (t == ntiles - 1);
      float p[2][4];
      #pragma unroll
      for (int n = 0; n < 2; n++) {
        int j = j0 + wk * 32 + n * 16 + ml;
        #pragma unroll
        for (int r = 0; r < 4; r++) {
          int q = q0 + wq * 16 + quad * 4 + r;
          float e = __expf(sacc[n][r]);
          p[n][r] = (lastt && j > q) ? 0.f : e;
          l_[r] += p[n][r];
        }
      }

      // P -> per-wave LDS (C->A layout; same-wave ordering via lgkmcnt)
      #pragma unroll
      for (int n = 0; n < 2; n++)
        #pragma unroll
        for (int r = 0; r < 4; r++)
          Ps[w][quad * 4 + r][n * 16 + ml] = f2bf(p[n][r]);

      // O += P·V over this wave's 32 keys: A = P[q=ml][k=quad*8+j],
      // B = V^T[d = n*16+ml][key = wk*32 + quad*8+j]
      short8 ap = *(const short8*)&Ps[w][ml][quad * 8];
      #pragma unroll
      for (int n = 0; n < 4; n++) {
        int dr = n * 16 + ml;
        short8 bv = *(const short8*)&VsT[dr * 64 + (((wk * 4 + quad) ^ (dr & 7)) * 8)];
        oacc[n] = __builtin_amdgcn_mfma_f32_16x16x32_bf16(ap, bv, oacc[n], 0, 0, 0);
      }
    }

    // combine the two key-halves (additive: no max rescaling exists)
    float lred[4];
    #pragma unroll
    for (int r = 0; r < 4; r++) {
      float lv = l_[r];
      lv += __shfl_xor(lv, 1, 64);
      lv += __shfl_xor(lv, 2, 64);
      lv += __shfl_xor(lv, 4, 64);
      lv += __shfl_xor(lv, 8, 64);
      lred[r] = lv;                 // per (quad,r): sum over this wave's keys
    }
    if (wk == 0) {
      #pragma unroll
      for (int n = 0; n < 4; n++)
        #pragma unroll
        for (int r = 0; r < 4; r++)
          Os[wq][quad * 4 + r][n * 16 + ml] = oacc[n][r];
      if (ml == 0) {
        #pragma unroll
        for (int r = 0; r < 4; r++) Ls[wq][quad * 4 + r] = lred[r];
      }
    }
    __syncthreads();
    if (wk == 1) {
      #pragma unroll
      for (int r = 0; r < 4; r++) {
        float inv = 1.f / (lred[r] + Ls[wq][quad * 4 + r]);
        int q = q0 + wq * 16 + quad * 4 + r;
        #pragma unroll
        for (int n = 0; n < 4; n++) {
          float o = oacc[n][r] + Os[wq][quad * 4 + r][n * 16 + ml];
          vhat[((size_t)(bb * NSEQ + q)) * DM + hb * DH + n * 16 + ml] =
              f2bf(o * inv);
        }
      }
    }
    // protect Os/Ls (and Ks/VsT) reuse by the next phase
    __syncthreads();
  }
}

// ---------------------------------------------------------------------------
extern "C" void kernel_launch(void* const* d_in, const int* in_sizes, int n_in,
                              void* d_out, int out_size, void* d_ws, size_t ws_size,
                              hipStream_t stream) {
  const float* X  = (const float*)d_in[0];
  const float* Wq = (const float*)d_in[1];
  const float* Wk = (const float*)d_in[2];
  const float* Wv = (const float*)d_in[3];
  const float* Wo = (const float*)d_in[4];
  const float* bo = (const float*)d_in[5];
  float* out = (float*)d_out;

  // ws (all bf16, 8 MB each): Qb | Kb | Vt[B,H,DH,N] | {Xb then vhat, aliased}
  // | WT (4 transposed weights, 8 MB total) = 40 MB
  const size_t NE = (size_t)BATCH * NSEQ * DM;   // 4,194,304
  u16* Qb   = (u16*)d_ws;
  u16* Kb   = Qb + NE;
  u16* Vt   = Kb + NE;
  u16* XbVh = Vt + NE;                           // Xb / vhat (disjoint lifetimes)
  u16* WT   = XbVh + NE;

  prep        <<<dim3(3072),      256, 0, stream>>>(X, Wq, Wk, Wv, Wo, XbVh, WT);
  gemm_qkv128 <<<dim3(8, 32, 3),  256, 0, stream>>>(XbVh, WT, Qb, Kb, Vt);
  flash_attn  <<<dim3(32, 32),    256, 0, stream>>>(Qb, Kb, Vt, XbVh);
  gemm_proj128<<<dim3(8, 32, 1),  256, 0, stream>>>(XbVh, WT + 3 * (size_t)DM * DM,
                                                    bo, out);
}

// Round 5
// 187.507 us; speedup vs baseline: 1.4558x; 1.0687x over previous
//
#include <hip/hip_runtime.h>
#include <hip/hip_bf16.h>
#include <math.h>

// Problem: B=2, N=2048, D_MODEL=1024, H=16, D_HEAD=64. fp32 in/out,
// bf16 MFMA internal (threshold is bf16-grade: 2% of max|ref|).
#define BATCH 2
#define NSEQ  2048
#define DM    1024
#define NH    16
#define DH    64
#define EPS_N 1e-6f

typedef unsigned short u16;
typedef __attribute__((ext_vector_type(8))) short short8;       // bf16x8 MFMA frag
typedef __attribute__((ext_vector_type(8))) unsigned short u16x8;
typedef __attribute__((ext_vector_type(4))) unsigned short u16x4;
typedef __attribute__((ext_vector_type(4))) float f32x4;

__device__ __forceinline__ u16 f2bf(float x) {
  __hip_bfloat16 h = __float2bfloat16(x);          // round-to-nearest-even
  return *reinterpret_cast<u16*>(&h);
}

// async 16B global->LDS (lane i lands at lds_base + 16*i)
__device__ __forceinline__ void gl_lds16(const u16* g, u16* lds_base) {
  __builtin_amdgcn_global_load_lds(
      (__attribute__((address_space(1))) void*)g,
      (__attribute__((address_space(3))) void*)lds_base, 16, 0, 0);
}

// ---------------------------------------------------------------------------
// Prep: blocks 0..1023 transpose+cast the 4 weight matrices (out[n][k] =
// bf16(in[k][n])); blocks 1024..3071 cast X fp32->bf16. grid 3072, 256 thr.
// ---------------------------------------------------------------------------
__global__ __launch_bounds__(256) void prep(
    const float* __restrict__ X,
    const float* __restrict__ w0, const float* __restrict__ w1,
    const float* __restrict__ w2, const float* __restrict__ w3,
    u16* __restrict__ Xb, u16* __restrict__ WT) {
  const int id = blockIdx.x, tid = threadIdx.x;
  if (id >= 1024) {                       // ---- cast X chunk
    size_t base = ((size_t)(id - 1024) * 256 + tid) * 8;
    float4 f0 = *(const float4*)&X[base];
    float4 f1 = *(const float4*)&X[base + 4];
    u16x8 v;
    v[0] = f2bf(f0.x); v[1] = f2bf(f0.y); v[2] = f2bf(f0.z); v[3] = f2bf(f0.w);
    v[4] = f2bf(f1.x); v[5] = f2bf(f1.y); v[6] = f2bf(f1.z); v[7] = f2bf(f1.w);
    *(u16x8*)&Xb[base] = v;
    return;
  }
  // ---- weight transpose tile
  const int z = id >> 8, xy = id & 255, bx = xy & 15, by = xy >> 4;
  const float* in = (z == 0) ? w0 : (z == 1) ? w1 : (z == 2) ? w2 : w3;
  u16* o = WT + (size_t)z * DM * DM;
  __shared__ u16 T[64][65];
  const int n0 = bx * 64, k0 = by * 64;
  #pragma unroll
  for (int i = 0; i < 4; i++) {
    int c = tid + 256 * i, row = c >> 4, col4 = c & 15;
    float4 f = *(const float4*)&in[(size_t)(k0 + row) * DM + n0 + col4 * 4];
    T[row][col4 * 4 + 0] = f2bf(f.x);
    T[row][col4 * 4 + 1] = f2bf(f.y);
    T[row][col4 * 4 + 2] = f2bf(f.z);
    T[row][col4 * 4 + 3] = f2bf(f.w);
  }
  __syncthreads();
  #pragma unroll
  for (int i = 0; i < 2; i++) {
    int c = tid + 256 * i, row = c >> 3, col8 = c & 7;
    u16x8 v;
    #pragma unroll
    for (int e = 0; e < 8; e++) v[e] = T[col8 * 8 + e][row];
    *(u16x8*)&o[(size_t)(n0 + row) * DM + k0 + col8 * 8] = v;
  }
}

// ===========================================================================
// v5: 64x128 GEMM mainloop (was 128x128). Same m97-style staging (BK=64,
// global_load_lds 16B, XOR-swizzled chunks: LDS row r holds global chunk g at
// slot g^(r&7)) but HALF the M-tile -> 2x the blocks -> 2x resident
// blocks/CU. LDS 24 KB (As 8 KB + Bs 16 KB): qkv grid 1536 = 6 blk/CU (75%
// wave cap, was 3 blk/37%); proj grid 512 = 2 blk/CU (was 1 blk = nothing to
// hide the per-K-step barrier drain). 256 thr, 4 waves 2x2; per-wave 32x64
// output = acc[2][4].
// ===========================================================================
#define GEMM64x128_MAINLOOP(Aptr, Btptr)                                       \
  __shared__ u16 As[64 * 64];                                                  \
  __shared__ u16 Bs[128 * 64];                                                 \
  const int tid = threadIdx.x, w = tid >> 6, lane = tid & 63;                  \
  const int ml = lane & 15, quad = lane >> 4;                                  \
  const int m0 = blockIdx.y * 64, n0 = blockIdx.x * 128;                       \
  const int wm = w & 1, wn = w >> 1;                                           \
  const int srow = lane >> 3;                 /* 0..7 within 8-row slab */     \
  const int scol = ((lane & 7) ^ srow) * 8;   /* swizzled global chunk */      \
  f32x4 acc[2][4];                                                             \
  _Pragma("unroll") for (int mi = 0; mi < 2; mi++)                             \
    _Pragma("unroll") for (int ni = 0; ni < 4; ni++)                           \
      _Pragma("unroll") for (int e = 0; e < 4; e++) acc[mi][ni][e] = 0.f;      \
  for (int k0 = 0; k0 < DM; k0 += 64) {                                        \
    __syncthreads();                                                           \
    _Pragma("unroll") for (int L = 0; L < 2; L++) {                            \
      int I = w * 2 + L;                      /* As slabs 0..7 */              \
      gl_lds16(Aptr + (size_t)(m0 + I * 8 + srow) * DM + k0 + scol,            \
               As + I * 512);                                                  \
    }                                                                          \
    _Pragma("unroll") for (int L = 0; L < 4; L++) {                            \
      int I = w * 4 + L;                      /* Bs slabs 0..15 */             \
      gl_lds16(Btptr + (size_t)(n0 + I * 8 + srow) * DM + k0 + scol,           \
               Bs + I * 512);                                                  \
    }                                                                          \
    __syncthreads();                                                           \
    _Pragma("unroll") for (int kk = 0; kk < 64; kk += 32) {                    \
      const int kc = kk >> 3;                 /* chunk base: 0 or 4 */         \
      short8 am[2], bn[4];                                                     \
      _Pragma("unroll") for (int i = 0; i < 2; i++) {                          \
        int ra = wm * 32 + i * 16 + ml;                                        \
        am[i] = *(const short8*)&As[ra * 64 + (((quad + kc) ^ (ra & 7)) * 8)]; \
      }                                                                        \
      _Pragma("unroll") for (int i = 0; i < 4; i++) {                          \
        int rb = wn * 64 + i * 16 + ml;                                        \
        bn[i] = *(const short8*)&Bs[rb * 64 + (((quad + kc) ^ (rb & 7)) * 8)]; \
      }                                                                        \
      _Pragma("unroll") for (int mi = 0; mi < 2; mi++)                         \
        _Pragma("unroll") for (int ni = 0; ni < 4; ni++)                       \
          acc[mi][ni] = __builtin_amdgcn_mfma_f32_16x16x32_bf16(               \
              am[mi], bn[ni], acc[mi][ni], 0, 0, 0);                           \
    }                                                                          \
  }

// ---------------------------------------------------------------------------
// QKV GEMM + fused L2 norm: Xb[4096][1024] bf16 @ W. z selects Q/K/V.
// Q,K: per-(head,token) L2-normalized in-register (Q also x1/8), -> [B,H,N,DH].
// V -> transposed [B,H,DH,N] (packed 8B stores). grid (8, 64, 3), 256 thr.
// Each wave's 64 cols = exactly one head (n0/64 + wn), so the L2-norm row
// reduce stays wave-local (sum over ni, then shfl over the 16 ml lanes).
// ---------------------------------------------------------------------------
__global__ __launch_bounds__(256) void gemm_qkv128(
    const u16* __restrict__ Xb, const u16* __restrict__ WT,
    u16* __restrict__ Qo, u16* __restrict__ Ko, u16* __restrict__ Vt) {
  const u16* Bt = WT + (size_t)blockIdx.z * DM * DM;
  GEMM64x128_MAINLOOP(Xb, Bt)
  const int z = blockIdx.z;
  if (z < 2) {
    u16* OutQK = (z == 0) ? Qo : Ko;
    const float qsc = (z == 0) ? 0.125f : 1.0f;     // fold softmax 1/sqrt(64)
    const int h = (n0 >> 6) + wn;                   // head of this wave's cols
    #pragma unroll
    for (int mi = 0; mi < 2; mi++) {
      int mrow0 = m0 + wm * 32 + mi * 16 + quad * 4;
      int b = mrow0 >> 11, tok0 = mrow0 & (NSEQ - 1);
      #pragma unroll
      for (int r = 0; r < 4; r++) {
        float ss = 0.f;
        #pragma unroll
        for (int ni = 0; ni < 4; ni++) ss += acc[mi][ni][r] * acc[mi][ni][r];
        ss += __shfl_xor(ss, 1, 64);
        ss += __shfl_xor(ss, 2, 64);
        ss += __shfl_xor(ss, 4, 64);
        ss += __shfl_xor(ss, 8, 64);    // sum over the 16 ml lanes (full row)
        float sc = qsc / (sqrtf(ss) + EPS_N);
        #pragma unroll
        for (int ni = 0; ni < 4; ni++)
          OutQK[((size_t)(b * NH + h) * NSEQ + tok0 + r) * DH + ni * 16 + ml] =
              f2bf(acc[mi][ni][r] * sc);
      }
    }
  } else {
    #pragma unroll
    for (int mi = 0; mi < 2; mi++) {
      int mrow0 = m0 + wm * 32 + mi * 16 + quad * 4;
      int b = mrow0 >> 11, tok0 = mrow0 & (NSEQ - 1);
      #pragma unroll
      for (int ni = 0; ni < 4; ni++) {
        int n = n0 + wn * 64 + ni * 16 + ml;
        int h = n >> 6, d = n & 63;
        u16x4 pk;
        #pragma unroll
        for (int r = 0; r < 4; r++) pk[r] = f2bf(acc[mi][ni][r]);
        *(u16x4*)&Vt[((size_t)(b * NH + h) * DH + d) * NSEQ + tok0] = pk;
      }
    }
  }
}

// ---------------------------------------------------------------------------
// Output projection: out = vhat[4096][1024] @ Wo + bo, fp32 out.
// grid (8, 64), 256 thr.
// ---------------------------------------------------------------------------
__global__ __launch_bounds__(256) void gemm_proj128(
    const u16* __restrict__ A, const u16* __restrict__ BtW,
    const float* __restrict__ bias, float* __restrict__ out) {
  GEMM64x128_MAINLOOP(A, BtW)
  #pragma unroll
  for (int ni = 0; ni < 4; ni++) {
    int n = n0 + wn * 64 + ni * 16 + ml;
    float bz = bias[n];
    #pragma unroll
    for (int mi = 0; mi < 2; mi++) {
      int mrow0 = m0 + wm * 32 + mi * 16 + quad * 4;
      #pragma unroll
      for (int r = 0; r < 4; r++)
        out[(size_t)(mrow0 + r) * DM + n] = acc[mi][ni][r] + bz;
    }
  }
}

// ---------------------------------------------------------------------------
// MFMA flash attention, causal, NO online max (|score|<=0.125 by L2 norm) ->
// O and l are ADDITIVE partials: split keys across waves, combine once/phase.
// Block = 32 q-rows/phase; pair {y, 63-y} -> exactly 33 tile-iters/block.
// Waves: wq = q-half (16 rows), wk = key-half (32 of 64 keys).
// Grid (bh=32, pair=32): XCD = flat%8 = bh%8 -> each XCD touches 4 heads' K/V
// (~2 MB, fits 4 MB L2). 256 thr.
//
// v4 structure kept (best so far: 54.1 us): reg-prefetch staging one tile
// ahead (T14), XOR-swizzled LDS (conflicts 7.3M -> 0.8M), 2 barriers/tile.
// ---------------------------------------------------------------------------
__global__ __launch_bounds__(256) void flash_attn(
    const u16* __restrict__ Qb, const u16* __restrict__ Kb,
    const u16* __restrict__ Vt, u16* __restrict__ vhat) {
  const int tid = threadIdx.x, w = tid >> 6, lane = tid & 63;
  const int ml = lane & 15, quad = lane >> 4;
  const int wq = w & 1, wk = w >> 1;
  const int bh = blockIdx.x;                  // 0..31 (= b*NH + h)
  const int bb = bh >> 4, hb = bh & 15;
  const int pair = blockIdx.y;                // 0..31
  const u16* Qh = Qb + (size_t)bh * NSEQ * DH;
  const u16* Kh = Kb + (size_t)bh * NSEQ * DH;
  const u16* Vth = Vt + (size_t)bh * DH * NSEQ;

  __shared__ u16 Ks [64 * 64];     // K[key][d], chunk s of row r = global s^r
  __shared__ u16 VsT[64 * 64];     // V^T[d][key], same scheme
  __shared__ u16 Ps [4][16][40];   // per-wave P[q16][key32] (C->A transform)
  __shared__ float Os[2][16][66];  // wk0's partial O [wq][q][d]
  __shared__ float Ls[2][16];      // wk0's partial l [wq][q]

  // staging geometry: wave w covers slabs {2w, 2w+1} (8 rows each) of both
  // tiles. lane -> row srow8 (within slab), LINEAR global chunk sch; the
  // ds_write lands at swizzled slot sch^srow8.
  const int srow8 = lane >> 3;                // 0..7 row within slab
  const int sch   = lane & 7;                 // linear global 16B chunk
  const int sslot = sch ^ srow8;              // swizzled LDS 16B slot

  for (int ph = 0; ph < 2; ph++) {
    const int qb32 = ph ? (63 - pair) : pair;
    const int q0 = qb32 * 32;
    const int ntiles = (qb32 >> 1) + 1;

    // Q A-frags for this wave's 16 rows: A[m=ml][k=quad*8+j]
    short8 aq[2];
    #pragma unroll
    for (int c = 0; c < 2; c++)
      aq[c] = *(const short8*)&Qh[(size_t)(q0 + wq * 16 + ml) * DH + c * 32 + quad * 8];

    f32x4 oacc[4];
    #pragma unroll
    for (int n = 0; n < 4; n++)
      #pragma unroll
      for (int e = 0; e < 4; e++) oacc[n][e] = 0.f;
    float l_[4] = {0.f, 0.f, 0.f, 0.f};

    // prologue: prefetch tile 0's K/V into regs (drained at first barrier)
    u16x8 kreg[2], vreg[2];
    #pragma unroll
    for (int i = 0; i < 2; i++) {
      int slab = w * 2 + i;
      kreg[i] = *(const u16x8*)&Kh[(size_t)(slab * 8 + srow8) * DH + sch * 8];
      vreg[i] = *(const u16x8*)&Vth[(size_t)(slab * 8 + srow8) * NSEQ + sch * 8];
    }

    for (int t = 0; t < ntiles; t++) {
      const int j0 = t * 64;
      __syncthreads();            // A: all waves done with prev tile's LDS;
                                  //    implicit vmcnt(0) = this tile's regs ok
      #pragma unroll
      for (int i = 0; i < 2; i++) {
        int slab = w * 2 + i;
        *(u16x8*)&Ks [(slab * 8 + srow8) * 64 + sslot * 8] = kreg[i];
        *(u16x8*)&VsT[(slab * 8 + srow8) * 64 + sslot * 8] = vreg[i];
      }
      __syncthreads();            // B: staged tiles visible to all waves

      // prefetch NEXT tile into regs — in flight during this tile's compute
      if (t + 1 < ntiles) {
        const int j1 = j0 + 64;
        #pragma unroll
        for (int i = 0; i < 2; i++) {
          int slab = w * 2 + i;
          kreg[i] = *(const u16x8*)&Kh[(size_t)(j1 + slab * 8 + srow8) * DH + sch * 8];
          vreg[i] = *(const u16x8*)&Vth[(size_t)(slab * 8 + srow8) * NSEQ + j1 + sch * 8];
        }
      }

      // S (16q x 32k): B-frag = K[key = wk*32 + n*16+ml][d = c*32+quad*8+j]
      f32x4 sacc[2];
      #pragma unroll
      for (int n = 0; n < 2; n++)
        #pragma unroll
        for (int e = 0; e < 4; e++) sacc[n][e] = 0.f;
      #pragma unroll
      for (int c = 0; c < 2; c++)
        #pragma unroll
        for (int n = 0; n < 2; n++) {
          int kr = wk * 32 + n * 16 + ml;
          short8 bf = *(const short8*)&Ks[kr * 64 + (((c * 4 + quad) ^ (kr & 7)) * 8)];
          sacc[n] = __builtin_amdgcn_mfma_f32_16x16x32_bf16(aq[c], bf, sacc[n], 0, 0, 0);
        }

      // p = exp(s), causal-masked on the last tile. C-layout: col=ml(key),
      // row=quad*4+r (q).
      const bool lastt = (t == ntiles - 1);
      float p[2][4];
      #pragma unroll
      for (int n = 0; n < 2; n++) {
        int j = j0 + wk * 32 + n * 16 + ml;
        #pragma unroll
        for (int r = 0; r < 4; r++) {
          int q = q0 + wq * 16 + quad * 4 + r;
          float e = __expf(sacc[n][r]);
          p[n][r] = (lastt && j > q) ? 0.f : e;
          l_[r] += p[n][r];
        }
      }

      // P -> per-wave LDS (C->A layout; same-wave ordering via lgkmcnt)
      #pragma unroll
      for (int n = 0; n < 2; n++)
        #pragma unroll
        for (int r = 0; r < 4; r++)
          Ps[w][quad * 4 + r][n * 16 + ml] = f2bf(p[n][r]);

      // O += P·V over this wave's 32 keys: A = P[q=ml][k=quad*8+j],
      // B = V^T[d = n*16+ml][key = wk*32 + quad*8+j]
      short8 ap = *(const short8*)&Ps[w][ml][quad * 8];
      #pragma unroll
      for (int n = 0; n < 4; n++) {
        int dr = n * 16 + ml;
        short8 bv = *(const short8*)&VsT[dr * 64 + (((wk * 4 + quad) ^ (dr & 7)) * 8)];
        oacc[n] = __builtin_amdgcn_mfma_f32_16x16x32_bf16(ap, bv, oacc[n], 0, 0, 0);
      }
    }

    // combine the two key-halves (additive: no max rescaling exists)
    float lred[4];
    #pragma unroll
    for (int r = 0; r < 4; r++) {
      float lv = l_[r];
      lv += __shfl_xor(lv, 1, 64);
      lv += __shfl_xor(lv, 2, 64);
      lv += __shfl_xor(lv, 4, 64);
      lv += __shfl_xor(lv, 8, 64);
      lred[r] = lv;                 // per (quad,r): sum over this wave's keys
    }
    if (wk == 0) {
      #pragma unroll
      for (int n = 0; n < 4; n++)
        #pragma unroll
        for (int r = 0; r < 4; r++)
          Os[wq][quad * 4 + r][n * 16 + ml] = oacc[n][r];
      if (ml == 0) {
        #pragma unroll
        for (int r = 0; r < 4; r++) Ls[wq][quad * 4 + r] = lred[r];
      }
    }
    __syncthreads();
    if (wk == 1) {
      #pragma unroll
      for (int r = 0; r < 4; r++) {
        float inv = 1.f / (lred[r] + Ls[wq][quad * 4 + r]);
        int q = q0 + wq * 16 + quad * 4 + r;
        #pragma unroll
        for (int n = 0; n < 4; n++) {
          float o = oacc[n][r] + Os[wq][quad * 4 + r][n * 16 + ml];
          vhat[((size_t)(bb * NSEQ + q)) * DM + hb * DH + n * 16 + ml] =
              f2bf(o * inv);
        }
      }
    }
    // protect Os/Ls (and Ks/VsT) reuse by the next phase
    __syncthreads();
  }
}

// ---------------------------------------------------------------------------
extern "C" void kernel_launch(void* const* d_in, const int* in_sizes, int n_in,
                              void* d_out, int out_size, void* d_ws, size_t ws_size,
                              hipStream_t stream) {
  const float* X  = (const float*)d_in[0];
  const float* Wq = (const float*)d_in[1];
  const float* Wk = (const float*)d_in[2];
  const float* Wv = (const float*)d_in[3];
  const float* Wo = (const float*)d_in[4];
  const float* bo = (const float*)d_in[5];
  float* out = (float*)d_out;

  // ws (all bf16, 8 MB each): Qb | Kb | Vt[B,H,DH,N] | {Xb then vhat, aliased}
  // | WT (4 transposed weights, 8 MB total) = 40 MB
  const size_t NE = (size_t)BATCH * NSEQ * DM;   // 4,194,304
  u16* Qb   = (u16*)d_ws;
  u16* Kb   = Qb + NE;
  u16* Vt   = Kb + NE;
  u16* XbVh = Vt + NE;                           // Xb / vhat (disjoint lifetimes)
  u16* WT   = XbVh + NE;

  prep        <<<dim3(3072),      256, 0, stream>>>(X, Wq, Wk, Wv, Wo, XbVh, WT);
  gemm_qkv128 <<<dim3(8, 64, 3),  256, 0, stream>>>(XbVh, WT, Qb, Kb, Vt);
  flash_attn  <<<dim3(32, 32),    256, 0, stream>>>(Qb, Kb, Vt, XbVh);
  gemm_proj128<<<dim3(8, 64, 1),  256, 0, stream>>>(XbVh, WT + 3 * (size_t)DM * DM,
                                                    bo, out);
}

// Round 6
// 182.162 us; speedup vs baseline: 1.4985x; 1.0293x over previous
//
#include <hip/hip_runtime.h>
#include <hip/hip_bf16.h>
#include <math.h>

// Problem: B=2, N=2048, D_MODEL=1024, H=16, D_HEAD=64. fp32 in/out,
// bf16 MFMA internal (threshold is bf16-grade: 2% of max|ref|).
#define BATCH 2
#define NSEQ  2048
#define DM    1024
#define NH    16
#define DH    64
#define EPS_N 1e-6f

typedef unsigned short u16;
typedef __attribute__((ext_vector_type(8))) short short8;       // bf16x8 MFMA frag
typedef __attribute__((ext_vector_type(8))) unsigned short u16x8;
typedef __attribute__((ext_vector_type(4))) unsigned short u16x4;
typedef __attribute__((ext_vector_type(4))) float f32x4;

__device__ __forceinline__ u16 f2bf(float x) {
  __hip_bfloat16 h = __float2bfloat16(x);          // round-to-nearest-even
  return *reinterpret_cast<u16*>(&h);
}

// async 16B global->LDS (lane i lands at lds_base + 16*i)
__device__ __forceinline__ void gl_lds16(const u16* g, u16* lds_base) {
  __builtin_amdgcn_global_load_lds(
      (__attribute__((address_space(1))) void*)g,
      (__attribute__((address_space(3))) void*)lds_base, 16, 0, 0);
}

// ---------------------------------------------------------------------------
// Prep: blocks 0..1023 transpose+cast the 4 weight matrices (out[n][k] =
// bf16(in[k][n])); blocks 1024..3071 cast X fp32->bf16. grid 3072, 256 thr.
// ---------------------------------------------------------------------------
__global__ __launch_bounds__(256) void prep(
    const float* __restrict__ X,
    const float* __restrict__ w0, const float* __restrict__ w1,
    const float* __restrict__ w2, const float* __restrict__ w3,
    u16* __restrict__ Xb, u16* __restrict__ WT) {
  const int id = blockIdx.x, tid = threadIdx.x;
  if (id >= 1024) {                       // ---- cast X chunk
    size_t base = ((size_t)(id - 1024) * 256 + tid) * 8;
    float4 f0 = *(const float4*)&X[base];
    float4 f1 = *(const float4*)&X[base + 4];
    u16x8 v;
    v[0] = f2bf(f0.x); v[1] = f2bf(f0.y); v[2] = f2bf(f0.z); v[3] = f2bf(f0.w);
    v[4] = f2bf(f1.x); v[5] = f2bf(f1.y); v[6] = f2bf(f1.z); v[7] = f2bf(f1.w);
    *(u16x8*)&Xb[base] = v;
    return;
  }
  // ---- weight transpose tile
  const int z = id >> 8, xy = id & 255, bx = xy & 15, by = xy >> 4;
  const float* in = (z == 0) ? w0 : (z == 1) ? w1 : (z == 2) ? w2 : w3;
  u16* o = WT + (size_t)z * DM * DM;
  __shared__ u16 T[64][65];
  const int n0 = bx * 64, k0 = by * 64;
  #pragma unroll
  for (int i = 0; i < 4; i++) {
    int c = tid + 256 * i, row = c >> 4, col4 = c & 15;
    float4 f = *(const float4*)&in[(size_t)(k0 + row) * DM + n0 + col4 * 4];
    T[row][col4 * 4 + 0] = f2bf(f.x);
    T[row][col4 * 4 + 1] = f2bf(f.y);
    T[row][col4 * 4 + 2] = f2bf(f.z);
    T[row][col4 * 4 + 3] = f2bf(f.w);
  }
  __syncthreads();
  #pragma unroll
  for (int i = 0; i < 2; i++) {
    int c = tid + 256 * i, row = c >> 3, col8 = c & 7;
    u16x8 v;
    #pragma unroll
    for (int e = 0; e < 8; e++) v[e] = T[col8 * 8 + e][row];
    *(u16x8*)&o[(size_t)(n0 + row) * DM + k0 + col8 * 8] = v;
  }
}

// ===========================================================================
// v5: 64x128 GEMM mainloop. m97-style staging (BK=64, global_load_lds 16B,
// XOR-swizzled chunks: LDS row r holds global chunk g at slot g^(r&7)).
// 256 thr, 4 waves 2x2; per-wave 32x64 output = acc[2][4]. LDS 24 KB.
// ===========================================================================
#define GEMM64x128_MAINLOOP(Aptr, Btptr)                                       \
  __shared__ u16 As[64 * 64];                                                  \
  __shared__ u16 Bs[128 * 64];                                                 \
  const int tid = threadIdx.x, w = tid >> 6, lane = tid & 63;                  \
  const int ml = lane & 15, quad = lane >> 4;                                  \
  const int m0 = blockIdx.y * 64, n0 = blockIdx.x * 128;                       \
  const int wm = w & 1, wn = w >> 1;                                           \
  const int srow = lane >> 3;                 /* 0..7 within 8-row slab */     \
  const int scol = ((lane & 7) ^ srow) * 8;   /* swizzled global chunk */      \
  f32x4 acc[2][4];                                                             \
  _Pragma("unroll") for (int mi = 0; mi < 2; mi++)                             \
    _Pragma("unroll") for (int ni = 0; ni < 4; ni++)                           \
      _Pragma("unroll") for (int e = 0; e < 4; e++) acc[mi][ni][e] = 0.f;      \
  for (int k0 = 0; k0 < DM; k0 += 64) {                                        \
    __syncthreads();                                                           \
    _Pragma("unroll") for (int L = 0; L < 2; L++) {                            \
      int I = w * 2 + L;                      /* As slabs 0..7 */              \
      gl_lds16(Aptr + (size_t)(m0 + I * 8 + srow) * DM + k0 + scol,            \
               As + I * 512);                                                  \
    }                                                                          \
    _Pragma("unroll") for (int L = 0; L < 4; L++) {                            \
      int I = w * 4 + L;                      /* Bs slabs 0..15 */             \
      gl_lds16(Btptr + (size_t)(n0 + I * 8 + srow) * DM + k0 + scol,           \
               Bs + I * 512);                                                  \
    }                                                                          \
    __syncthreads();                                                           \
    _Pragma("unroll") for (int kk = 0; kk < 64; kk += 32) {                    \
      const int kc = kk >> 3;                 /* chunk base: 0 or 4 */         \
      short8 am[2], bn[4];                                                     \
      _Pragma("unroll") for (int i = 0; i < 2; i++) {                          \
        int ra = wm * 32 + i * 16 + ml;                                        \
        am[i] = *(const short8*)&As[ra * 64 + (((quad + kc) ^ (ra & 7)) * 8)]; \
      }                                                                        \
      _Pragma("unroll") for (int i = 0; i < 4; i++) {                          \
        int rb = wn * 64 + i * 16 + ml;                                        \
        bn[i] = *(const short8*)&Bs[rb * 64 + (((quad + kc) ^ (rb & 7)) * 8)]; \
      }                                                                        \
      _Pragma("unroll") for (int mi = 0; mi < 2; mi++)                         \
        _Pragma("unroll") for (int ni = 0; ni < 4; ni++)                       \
          acc[mi][ni] = __builtin_amdgcn_mfma_f32_16x16x32_bf16(               \
              am[mi], bn[ni], acc[mi][ni], 0, 0, 0);                           \
    }                                                                          \
  }

// ---------------------------------------------------------------------------
// QKV GEMM + fused L2 norm: Xb[4096][1024] bf16 @ W. z selects Q/K/V.
// Q,K: per-(head,token) L2-normalized in-register (Q also x1/8), -> [B,H,N,DH].
// V -> transposed [B,H,DH,N] (packed 8B stores). grid (8, 64, 3), 256 thr.
// ---------------------------------------------------------------------------
__global__ __launch_bounds__(256) void gemm_qkv128(
    const u16* __restrict__ Xb, const u16* __restrict__ WT,
    u16* __restrict__ Qo, u16* __restrict__ Ko, u16* __restrict__ Vt) {
  const u16* Bt = WT + (size_t)blockIdx.z * DM * DM;
  GEMM64x128_MAINLOOP(Xb, Bt)
  const int z = blockIdx.z;
  if (z < 2) {
    u16* OutQK = (z == 0) ? Qo : Ko;
    const float qsc = (z == 0) ? 0.125f : 1.0f;     // fold softmax 1/sqrt(64)
    const int h = (n0 >> 6) + wn;                   // head of this wave's cols
    #pragma unroll
    for (int mi = 0; mi < 2; mi++) {
      int mrow0 = m0 + wm * 32 + mi * 16 + quad * 4;
      int b = mrow0 >> 11, tok0 = mrow0 & (NSEQ - 1);
      #pragma unroll
      for (int r = 0; r < 4; r++) {
        float ss = 0.f;
        #pragma unroll
        for (int ni = 0; ni < 4; ni++) ss += acc[mi][ni][r] * acc[mi][ni][r];
        ss += __shfl_xor(ss, 1, 64);
        ss += __shfl_xor(ss, 2, 64);
        ss += __shfl_xor(ss, 4, 64);
        ss += __shfl_xor(ss, 8, 64);    // sum over the 16 ml lanes (full row)
        float sc = qsc / (sqrtf(ss) + EPS_N);
        #pragma unroll
        for (int ni = 0; ni < 4; ni++)
          OutQK[((size_t)(b * NH + h) * NSEQ + tok0 + r) * DH + ni * 16 + ml] =
              f2bf(acc[mi][ni][r] * sc);
      }
    }
  } else {
    #pragma unroll
    for (int mi = 0; mi < 2; mi++) {
      int mrow0 = m0 + wm * 32 + mi * 16 + quad * 4;
      int b = mrow0 >> 11, tok0 = mrow0 & (NSEQ - 1);
      #pragma unroll
      for (int ni = 0; ni < 4; ni++) {
        int n = n0 + wn * 64 + ni * 16 + ml;
        int h = n >> 6, d = n & 63;
        u16x4 pk;
        #pragma unroll
        for (int r = 0; r < 4; r++) pk[r] = f2bf(acc[mi][ni][r]);
        *(u16x4*)&Vt[((size_t)(b * NH + h) * DH + d) * NSEQ + tok0] = pk;
      }
    }
  }
}

// ---------------------------------------------------------------------------
// Output projection: out = vhat[4096][1024] @ Wo + bo, fp32 out.
// grid (8, 64), 256 thr.
// ---------------------------------------------------------------------------
__global__ __launch_bounds__(256) void gemm_proj128(
    const u16* __restrict__ A, const u16* __restrict__ BtW,
    const float* __restrict__ bias, float* __restrict__ out) {
  GEMM64x128_MAINLOOP(A, BtW)
  #pragma unroll
  for (int ni = 0; ni < 4; ni++) {
    int n = n0 + wn * 64 + ni * 16 + ml;
    float bz = bias[n];
    #pragma unroll
    for (int mi = 0; mi < 2; mi++) {
      int mrow0 = m0 + wm * 32 + mi * 16 + quad * 4;
      #pragma unroll
      for (int r = 0; r < 4; r++)
        out[(size_t)(mrow0 + r) * DM + n] = acc[mi][ni][r] + bz;
    }
  }
}

// ---------------------------------------------------------------------------
// MFMA flash attention, causal, NO online max (|score|<=0.125 by L2 norm) ->
// O and l are ADDITIVE partials: split keys across waves, combine once/phase.
//
// v6: QBLK=64 per block, 512 thr = 8 waves (4 q-waves wq x 2 key-halves wk).
// Halves (per unit of output) the K/V staging traffic, ds_writes, barriers,
// and block prologues vs v4's QBLK=32 (each staged 64-key tile now serves 64
// q-rows). Grid (bh=32, pairY=16); pair {y, 31-y} -> qb64+1 tiles, 33/block
// balanced. XCD = flat%8 = bh%8 preserved (4 heads' K/V per XCD, L2-fit).
// Staging: reg-prefetch one tile ahead (v4 scheme); each wave stages 1 slab
// (8 rows) of K and of V^T. XOR-swizzled LDS (row r, chunk slot s holds
// global chunk s^(r&7)); reads XOR chunk with row&7. LDS ~43.8 KB.
// ---------------------------------------------------------------------------
__global__ __launch_bounds__(512) void flash_attn(
    const u16* __restrict__ Qb, const u16* __restrict__ Kb,
    const u16* __restrict__ Vt, u16* __restrict__ vhat) {
  const int tid = threadIdx.x, w = tid >> 6, lane = tid & 63;
  const int ml = lane & 15, quad = lane >> 4;
  const int wq = w & 3, wk = w >> 2;
  const int bh = blockIdx.x;                  // 0..31 (= b*NH + h)
  const int bb = bh >> 4, hb = bh & 15;
  const int pairY = blockIdx.y;               // 0..15
  const u16* Qh = Qb + (size_t)bh * NSEQ * DH;
  const u16* Kh = Kb + (size_t)bh * NSEQ * DH;
  const u16* Vth = Vt + (size_t)bh * DH * NSEQ;

  __shared__ u16 Ks [64 * 64];     // K[key][d], chunk s of row r = global s^r
  __shared__ u16 VsT[64 * 64];     // V^T[d][key], same scheme
  __shared__ u16 Ps [8][16][40];   // per-wave P[q16][key32] (C->A transform)
  __shared__ float Os[4][16][66];  // wk0's partial O [wq][q][d]
  __shared__ float Ls[4][16];      // wk0's partial l [wq][q]

  // staging geometry: wave w stages slab w (8 rows) of K and of V^T.
  // lane -> row srow8, LINEAR global chunk sch; ds_write lands at swizzled
  // slot sch^srow8.
  const int srow8 = lane >> 3;                // 0..7 row within slab
  const int sch   = lane & 7;                 // linear global 16B chunk
  const int sslot = sch ^ srow8;              // swizzled LDS 16B slot

  for (int ph = 0; ph < 2; ph++) {
    const int qb64 = ph ? (31 - pairY) : pairY;
    const int q0 = qb64 * 64;
    const int ntiles = qb64 + 1;

    // Q A-frags for this wave's 16 rows: A[m=ml][k=quad*8+j]
    short8 aq[2];
    #pragma unroll
    for (int c = 0; c < 2; c++)
      aq[c] = *(const short8*)&Qh[(size_t)(q0 + wq * 16 + ml) * DH + c * 32 + quad * 8];

    f32x4 oacc[4];
    #pragma unroll
    for (int n = 0; n < 4; n++)
      #pragma unroll
      for (int e = 0; e < 4; e++) oacc[n][e] = 0.f;
    float l_[4] = {0.f, 0.f, 0.f, 0.f};

    // prologue: prefetch tile 0's K/V slab into regs
    u16x8 kreg, vreg;
    kreg = *(const u16x8*)&Kh[(size_t)(w * 8 + srow8) * DH + sch * 8];
    vreg = *(const u16x8*)&Vth[(size_t)(w * 8 + srow8) * NSEQ + sch * 8];

    for (int t = 0; t < ntiles; t++) {
      const int j0 = t * 64;
      __syncthreads();            // A: all waves done with prev tile's LDS;
                                  //    implicit vmcnt(0) = this tile's regs ok
      *(u16x8*)&Ks [(w * 8 + srow8) * 64 + sslot * 8] = kreg;
      *(u16x8*)&VsT[(w * 8 + srow8) * 64 + sslot * 8] = vreg;
      __syncthreads();            // B: staged tiles visible to all waves

      // prefetch NEXT tile into regs — in flight during this tile's compute
      if (t + 1 < ntiles) {
        const int j1 = j0 + 64;
        kreg = *(const u16x8*)&Kh[(size_t)(j1 + w * 8 + srow8) * DH + sch * 8];
        vreg = *(const u16x8*)&Vth[(size_t)(w * 8 + srow8) * NSEQ + j1 + sch * 8];
      }

      // S (16q x 32k): B-frag = K[key = wk*32 + n*16+ml][d = c*32+quad*8+j]
      f32x4 sacc[2];
      #pragma unroll
      for (int n = 0; n < 2; n++)
        #pragma unroll
        for (int e = 0; e < 4; e++) sacc[n][e] = 0.f;
      #pragma unroll
      for (int c = 0; c < 2; c++)
        #pragma unroll
        for (int n = 0; n < 2; n++) {
          int kr = wk * 32 + n * 16 + ml;
          short8 bf = *(const short8*)&Ks[kr * 64 + (((c * 4 + quad) ^ (kr & 7)) * 8)];
          sacc[n] = __builtin_amdgcn_mfma_f32_16x16x32_bf16(aq[c], bf, sacc[n], 0, 0, 0);
        }

      // p = exp(s), causal-masked on the last tile. C-layout: col=ml(key),
      // row=quad*4+r (q).
      const bool lastt = (t == ntiles - 1);
      float p[2][4];
      #pragma unroll
      for (int n = 0; n < 2; n++) {
        int j = j0 + wk * 32 + n * 16 + ml;
        #pragma unroll
        for (int r = 0; r < 4; r++) {
          int q = q0 + wq * 16 + quad * 4 + r;
          float e = __expf(sacc[n][r]);
          p[n][r] = (lastt && j > q) ? 0.f : e;
          l_[r] += p[n][r];
        }
      }

      // P -> per-wave LDS (C->A layout; same-wave ordering via lgkmcnt)
      #pragma unroll
      for (int n = 0; n < 2; n++)
        #pragma unroll
        for (int r = 0; r < 4; r++)
          Ps[w][quad * 4 + r][n * 16 + ml] = f2bf(p[n][r]);

      // O += P·V over this wave's 32 keys: A = P[q=ml][k=quad*8+j],
      // B = V^T[d = n*16+ml][key = wk*32 + quad*8+j]
      short8 ap = *(const short8*)&Ps[w][ml][quad * 8];
      #pragma unroll
      for (int n = 0; n < 4; n++) {
        int dr = n * 16 + ml;
        short8 bv = *(const short8*)&VsT[dr * 64 + (((wk * 4 + quad) ^ (dr & 7)) * 8)];
        oacc[n] = __builtin_amdgcn_mfma_f32_16x16x32_bf16(ap, bv, oacc[n], 0, 0, 0);
      }
    }

    // combine the two key-halves (additive: no max rescaling exists)
    float lred[4];
    #pragma unroll
    for (int r = 0; r < 4; r++) {
      float lv = l_[r];
      lv += __shfl_xor(lv, 1, 64);
      lv += __shfl_xor(lv, 2, 64);
      lv += __shfl_xor(lv, 4, 64);
      lv += __shfl_xor(lv, 8, 64);
      lred[r] = lv;                 // per (quad,r): sum over this wave's keys
    }
    if (wk == 0) {
      #pragma unroll
      for (int n = 0; n < 4; n++)
        #pragma unroll
        for (int r = 0; r < 4; r++)
          Os[wq][quad * 4 + r][n * 16 + ml] = oacc[n][r];
      if (ml == 0) {
        #pragma unroll
        for (int r = 0; r < 4; r++) Ls[wq][quad * 4 + r] = lred[r];
      }
    }
    __syncthreads();
    if (wk == 1) {
      #pragma unroll
      for (int r = 0; r < 4; r++) {
        float inv = 1.f / (lred[r] + Ls[wq][quad * 4 + r]);
        int q = q0 + wq * 16 + quad * 4 + r;
        #pragma unroll
        for (int n = 0; n < 4; n++) {
          float o = oacc[n][r] + Os[wq][quad * 4 + r][n * 16 + ml];
          vhat[((size_t)(bb * NSEQ + q)) * DM + hb * DH + n * 16 + ml] =
              f2bf(o * inv);
        }
      }
    }
    // protect Os/Ls (and Ks/VsT) reuse by the next phase
    __syncthreads();
  }
}

// ---------------------------------------------------------------------------
extern "C" void kernel_launch(void* const* d_in, const int* in_sizes, int n_in,
                              void* d_out, int out_size, void* d_ws, size_t ws_size,
                              hipStream_t stream) {
  const float* X  = (const float*)d_in[0];
  const float* Wq = (const float*)d_in[1];
  const float* Wk = (const float*)d_in[2];
  const float* Wv = (const float*)d_in[3];
  const float* Wo = (const float*)d_in[4];
  const float* bo = (const float*)d_in[5];
  float* out = (float*)d_out;

  // ws (all bf16, 8 MB each): Qb | Kb | Vt[B,H,DH,N] | {Xb then vhat, aliased}
  // | WT (4 transposed weights, 8 MB total) = 40 MB
  const size_t NE = (size_t)BATCH * NSEQ * DM;   // 4,194,304
  u16* Qb   = (u16*)d_ws;
  u16* Kb   = Qb + NE;
  u16* Vt   = Kb + NE;
  u16* XbVh = Vt + NE;                           // Xb / vhat (disjoint lifetimes)
  u16* WT   = XbVh + NE;

  prep        <<<dim3(3072),      256, 0, stream>>>(X, Wq, Wk, Wv, Wo, XbVh, WT);
  gemm_qkv128 <<<dim3(8, 64, 3),  256, 0, stream>>>(XbVh, WT, Qb, Kb, Vt);
  flash_attn  <<<dim3(32, 16),    512, 0, stream>>>(Qb, Kb, Vt, XbVh);
  gemm_proj128<<<dim3(8, 64, 1),  256, 0, stream>>>(XbVh, WT + 3 * (size_t)DM * DM,
                                                    bo, out);
}